// Round 14
// baseline (538.890 us; speedup 1.0000x reference)
//
#include <hip/hip_runtime.h>

#define H 128
#define LN_EPS 1e-5f

typedef _Float16 half8 __attribute__((ext_vector_type(8)));
typedef float floatx4 __attribute__((ext_vector_type(4)));

__device__ __forceinline__ float silu_f(float x) { return x / (1.0f + __expf(-x)); }

__device__ __forceinline__ half8 cvt8(float4 a, float4 b) {
    half8 o;
    o[0] = (_Float16)a.x; o[1] = (_Float16)a.y; o[2] = (_Float16)a.z; o[3] = (_Float16)a.w;
    o[4] = (_Float16)b.x; o[5] = (_Float16)b.y; o[6] = (_Float16)b.z; o[7] = (_Float16)b.w;
    return o;
}

// ---------------------------------------------------------------------------
// fp32 -> fp16 h table
// ---------------------------------------------------------------------------
__global__ void cvt_h16(const float* __restrict__ src, _Float16* __restrict__ dst,
                        int total8)
{
    int i = blockIdx.x * blockDim.x + threadIdx.x;
    if (i >= total8) return;
    const float4* p = (const float4*)(src + i * 8);
    *(half8*)(dst + i * 8) = cvt8(p[0], p[1]);
}

// All four weight matrices -> fragment-order fp16 slabs.
// wef: 14 slabs (eW1 10 + eW2 4); nwf: 13 slabs (nW1 9 + nW2 4).
// WF[slab][f][lane][j] = W[k = s*32+(lane>>4)*8+j][col = f*16+(lane&15)]
__global__ void cvt_weights(const float* __restrict__ eW1, const float* __restrict__ eW2,
                            const float* __restrict__ nW1, const float* __restrict__ nW2,
                            _Float16* __restrict__ wef, _Float16* __restrict__ nwf)
{
    int i = blockIdx.x * blockDim.x + threadIdx.x;
    if (i >= 27 * 4096) return;
    int j    = i & 7;
    int lane = (i >> 3) & 63;
    int f    = (i >> 9) & 7;
    int slab = i >> 12;
    int col  = f * 16 + (lane & 15);
    int kin  = (lane >> 4) * 8 + j;
    const float* W; int K, s; _Float16* dst; int di;
    if (slab < 10)      { W = eW1; K = 304; s = slab;      dst = wef; di = i; }
    else if (slab < 14) { W = eW2; K = 128; s = slab - 10; dst = wef; di = i; }
    else if (slab < 23) { W = nW1; K = 272; s = slab - 14; dst = nwf; di = i - 14 * 4096; }
    else                { W = nW2; K = 128; s = slab - 23; dst = nwf; di = i - 14 * 4096; }
    int k = s * 32 + kin;
    dst[di] = (k < K) ? (_Float16)W[k * H + col] : (_Float16)0.0f;
}

// ---------------------------------------------------------------------------
// Full counting sort by dst (N bins).
// ---------------------------------------------------------------------------
__global__ void hist2_kernel(const int* __restrict__ edst, int E,
                             int* __restrict__ cnt)
{
    for (int e = blockIdx.x * blockDim.x + threadIdx.x; e < E;
         e += gridDim.x * blockDim.x)
        atomicAdd(&cnt[edst[e]], 1);
}

__global__ void __launch_bounds__(1024)
scan2_kernel(const int* __restrict__ cnt, int* __restrict__ base,
             int* __restrict__ cursor, int N)
{
    __shared__ int wsum[16];
    __shared__ int woff[16];
    const int tid  = threadIdx.x;
    const int lane = tid & 63;
    const int w    = tid >> 6;
    const int chunk = (N + 1023) >> 10;
    const int lo = min(tid * chunk, N);
    const int hi = min(lo + chunk, N);
    int s = 0;
    for (int i = lo; i < hi; i++) s += cnt[i];
    // inclusive shuffle-scan within wave
    int v = s;
    #pragma unroll
    for (int d = 1; d < 64; d <<= 1) {
        int u = __shfl_up(v, d);
        if (lane >= d) v += u;
    }
    if (lane == 63) wsum[w] = v;
    __syncthreads();
    if (tid == 0) {
        int r = 0;
        #pragma unroll
        for (int i = 0; i < 16; i++) { int c = wsum[i]; woff[i] = r; r += c; }
    }
    __syncthreads();
    int run = woff[w] + (v - s);   // exclusive prefix for this thread's chunk
    for (int i = lo; i < hi; i++) {
        base[i] = run; cursor[i] = run;
        run += cnt[i];
    }
}

__global__ void binfo_kernel(const int* __restrict__ base, int N, int bsz, int E,
                             int* __restrict__ binfo)
{
    int b = threadIdx.x;
    if (b < 8) {
        int lo = min(b * bsz, N);
        int hi = min((b + 1) * bsz, N);
        int blo = (lo >= N) ? E : base[lo];
        int bhi = (hi >= N) ? E : base[hi];
        binfo[8 + b] = blo;
        binfo[b]     = bhi - blo;
    }
}

__global__ void scatter2_kernel(const int* __restrict__ edst, int E,
                                int* __restrict__ cursor, int* __restrict__ perm)
{
    for (int e = blockIdx.x * blockDim.x + threadIdx.x; e < E;
         e += gridDim.x * blockDim.x) {
        int p = atomicAdd(&cursor[edst[e]], 1);
        perm[p] = e;
    }
}

// ---------------------------------------------------------------------------
// Edge kernel: 64-edge tiles, dst-sorted.  2-slab LDS B dbuf + 3-deep reg
// prefetch (unchanged from R13).  NEW: per-thread meta in registers with the
// 3-hop meta chain for tile t+1 prefetched at MLP1 steps 0/3/6 of tile t,
// and next-tile A-gathers issued after MLP2 (a[] is dead then) so they land
// under the epilogue.  Per-tile serial chain = MFMA + epilogue only.
// ---------------------------------------------------------------------------
__global__ void __launch_bounds__(256, 4)
edge_mfma(const _Float16* __restrict__ h16,
          const int* __restrict__ perm, const int* __restrict__ binfo,
          const int* __restrict__ esrc, const int* __restrict__ edst,
          const int* __restrict__ erel, const int* __restrict__ ncol,
          const int* __restrict__ nrole,
          const float* __restrict__ rel_emb, const float* __restrict__ role_emb,
          const float* __restrict__ col_emb,
          const _Float16* __restrict__ wef,   // [14][4096] fragment-order
          const float* __restrict__ eb1, const float* __restrict__ eb2,
          float* __restrict__ agg)
{
    __shared__ __align__(16) unsigned char uR[16896];  // sB 2x8KB / M [32][132] f32
    __shared__ __align__(16) _Float16 sY[64 * 136];
    __shared__ int sDst[64];
    __shared__ float sRelE[128], sRoleE[48], sColE[24];

    _Float16* sB = (_Float16*)uR;
    float*    M  = (float*)uR;

    const int tid  = threadIdx.x;
    const int lane = tid & 63;
    const int wv   = tid >> 6;
    const int lm   = lane & 15;
    const int lh   = lane >> 4;

    if (tid < 128) sRelE[tid] = rel_emb[tid];
    if (tid < 48)  sRoleE[tid] = role_emb[tid];
    if (tid < 24)  sColE[tid] = col_emb[tid];

    const int bucket = blockIdx.x;
    const int bcount = binfo[bucket];
    const int bbase  = binfo[8 + bucket];
    const int gy     = gridDim.y;

    const int r0 = wv * 16 + lm;          // this thread's A row
    const _Float16* wp = wef + tid * 16;

    float bias1[8], bias2[8];
    #pragma unroll
    for (int f = 0; f < 8; f++) { bias1[f] = eb1[f * 16 + lm]; bias2[f] = eb2[f * 16 + lm]; }

    // ---- prologue: meta + A for the first tile (per-thread, row r0) ----
    int mSrc = 0, mDst = -1, mRel = 0, mRS = 0, mRD = 0, mCS = 0, mCD = 0;
    half8 a[8];
    const int t0 = blockIdx.y;
    if (t0 * 64 < bcount) {
        int idx   = t0 * 64 + r0;
        int valid = idx < bcount;
        int e = perm[bbase + (valid ? idx : 0)];
        int s = esrc[e], d = edst[e];
        mSrc = s; mRel = erel[e];
        mRS = nrole[s]; mRD = nrole[d];
        mCS = ncol[s];  mCD = ncol[d];
        mDst = valid ? d : -1;
        int adst = mDst < 0 ? mSrc : mDst;
        const _Float16* sp = &h16[(size_t)mSrc * H + lh * 8];
        const _Float16* dp = &h16[(size_t)adst * H + lh * 8];
        #pragma unroll
        for (int q = 0; q < 4; q++) a[q]     = *(const half8*)(sp + q * 32);
        #pragma unroll
        for (int q = 0; q < 4; q++) a[4 + q] = *(const half8*)(dp + q * 32);
    }

    for (int t = t0; t * 64 < bcount; t += gy)
    {
        const bool hasNext = (t + gy) * 64 < bcount;
        int pE = 0, pSrc = 0, pDstR = 0, pRel = 0, pRS = 0, pRD = 0, pCS = 0, pCD = 0, pValid = 0;

        __syncthreads();   // previous tile fully consumed (M reads, sB, sDst)
        if (lh == 0) sDst[r0] = mDst;

        // ---- B prologue: slab 0 -> LDS slot 0; slabs 1,2 -> pf regs ----
        half8 pfa[3], pfb[3];
        {
            half8 s0a = *(const half8*)(wp);
            half8 s0b = *(const half8*)(wp + 8);
            *(half8*)&sB[tid * 16]     = s0a;
            *(half8*)&sB[tid * 16 + 8] = s0b;
            pfa[1] = *(const half8*)(wp + 1 * 4096);
            pfb[1] = *(const half8*)(wp + 1 * 4096 + 8);
            pfa[2] = *(const half8*)(wp + 2 * 4096);
            pfb[2] = *(const half8*)(wp + 2 * 4096 + 8);
        }

        floatx4 acc[8];
        #pragma unroll
        for (int f = 0; f < 8; f++) acc[f] = (floatx4){0.f, 0.f, 0.f, 0.f};

        __syncthreads();   // slab0 + sDst visible

        // ---- MLP1: steps 0..9; next-tile meta chain at steps 0/3/6 ----
        #pragma unroll
        for (int s = 0; s < 10; s++) {
            if (s + 3 <= 13) {
                pfa[s % 3] = *(const half8*)(wp + (s + 3) * 4096);
                pfb[s % 3] = *(const half8*)(wp + (s + 3) * 4096 + 8);
            }
            if (s == 0 && hasNext) {
                int nidx = (t + gy) * 64 + r0;
                pValid = nidx < bcount;
                pE = perm[bbase + (pValid ? nidx : 0)];
            }
            if (s == 3 && hasNext) {
                pSrc  = esrc[pE];
                pDstR = edst[pE];
                pRel  = erel[pE];
            }
            if (s == 6 && hasNext) {
                pRS = nrole[pSrc]; pRD = nrole[pDstR];
                pCS = ncol[pSrc];  pCD = ncol[pDstR];
            }
            half8 af;
            if (s < 8) {
                af = a[s];
            } else if (s == 8) {
                const float* p = (lh == 0) ? &sRelE[mRel * 16]
                               : (lh == 1) ? &sRelE[mRel * 16 + 8]
                               : (lh == 2) ? &sRoleE[mRS * 8]
                                           : &sRoleE[mRD * 8];
                #pragma unroll
                for (int j = 0; j < 8; j++) af[j] = (_Float16)p[j];
            } else {
                if (lh < 2) {
                    const float* p = (lh == 0) ? &sColE[mCS * 8] : &sColE[mCD * 8];
                    #pragma unroll
                    for (int j = 0; j < 8; j++) af[j] = (_Float16)p[j];
                } else {
                    #pragma unroll
                    for (int j = 0; j < 8; j++) af[j] = (_Float16)0.0f;
                }
            }
            #pragma unroll
            for (int f = 0; f < 8; f++) {
                half8 bf = *(const half8*)&sB[(s & 1) * 4096 + (f * 64 + lane) * 8];
                acc[f] = __builtin_amdgcn_mfma_f32_16x16x32_f16(af, bf, acc[f], 0, 0, 0);
            }
            {
                _Float16* wdst = &sB[((s + 1) & 1) * 4096 + tid * 16];
                *(half8*)(wdst)     = pfa[(s + 1) % 3];
                *(half8*)(wdst + 8) = pfb[(s + 1) % 3];
            }
            __syncthreads();
        }

        // ---- transition (wave-local rows): sY = silu(acc + eb1) ----
        #pragma unroll
        for (int f = 0; f < 8; f++) {
            const int col = f * 16 + lm;
            #pragma unroll
            for (int v = 0; v < 4; v++) {
                const int row = wv * 16 + lh * 4 + v;
                sY[row * 136 + col] = (_Float16)silu_f(acc[f][v] + bias1[f]);
            }
        }
        asm volatile("s_waitcnt lgkmcnt(0)" ::: "memory");

        floatx4 acc2[8];
        #pragma unroll
        for (int f = 0; f < 8; f++) acc2[f] = (floatx4){0.f, 0.f, 0.f, 0.f};

        // ---- MLP2: steps 10..13 ----
        #pragma unroll
        for (int s2 = 0; s2 < 4; s2++) {
            const int s = 10 + s2;
            if (s + 3 <= 13) {   // s == 10 only
                pfa[s % 3] = *(const half8*)(wp + (s + 3) * 4096);
                pfb[s % 3] = *(const half8*)(wp + (s + 3) * 4096 + 8);
            }
            half8 af = *(const half8*)&sY[r0 * 136 + s2 * 32 + lh * 8];
            #pragma unroll
            for (int f = 0; f < 8; f++) {
                half8 bf = *(const half8*)&sB[(s & 1) * 4096 + (f * 64 + lane) * 8];
                acc2[f] = __builtin_amdgcn_mfma_f32_16x16x32_f16(af, bf, acc2[f], 0, 0, 0);
            }
            if (s <= 12) {
                _Float16* wdst = &sB[((s + 1) & 1) * 4096 + tid * 16];
                *(half8*)(wdst)     = pfa[(s + 1) % 3];
                *(half8*)(wdst + 8) = pfb[(s + 1) % 3];
            }
            if (s2 < 3) __syncthreads();
        }

        // ---- commit prefetched meta; issue next-tile A into dead a[] ----
        if (hasNext) {
            mSrc = pSrc; mRel = pRel; mRS = pRS; mRD = pRD; mCS = pCS; mCD = pCD;
            mDst = pValid ? pDstR : -1;
            int adst = mDst < 0 ? mSrc : mDst;
            const _Float16* sp = &h16[(size_t)mSrc * H + lh * 8];
            const _Float16* dp = &h16[(size_t)adst * H + lh * 8];
            #pragma unroll
            for (int q = 0; q < 4; q++) a[q]     = *(const half8*)(sp + q * 32);
            #pragma unroll
            for (int q = 0; q < 4; q++) a[4 + q] = *(const half8*)(dp + q * 32);
        }

        // ---- epilogue: 2 passes; bulk-load regs then run-length atomics ----
        #pragma unroll
        for (int p = 0; p < 2; p++) {
            __syncthreads();   // sB reads (and previous M reads) complete
            if ((wv >> 1) == p) {
                #pragma unroll
                for (int f = 0; f < 8; f++) {
                    const int col = f * 16 + lm;
                    #pragma unroll
                    for (int v = 0; v < 4; v++) {
                        const int row = wv * 16 + lh * 4 + v;
                        M[(row & 31) * 132 + col] = silu_f(acc2[f][v] + bias2[f]);
                    }
                }
            }
            __syncthreads();
            {
                const int c  = tid & 127;
                const int rb = (tid >> 7) * 16;
                float m[16]; int dd[16];
                #pragma unroll
                for (int i = 0; i < 16; i++) {
                    m[i]  = M[(rb + i) * 132 + c];
                    dd[i] = sDst[p * 32 + rb + i];
                }
                float acz = 0.0f; int cur = -1;
                #pragma unroll
                for (int i = 0; i < 16; i++) {
                    if (dd[i] != cur) {
                        if (cur >= 0) unsafeAtomicAdd(&agg[cur * H + c], acz);
                        acz = 0.0f; cur = dd[i];
                    }
                    if (dd[i] >= 0) acz += m[i];
                }
                if (cur >= 0) unsafeAtomicAdd(&agg[cur * H + c], acz);
            }
        }
    }
}

// ---------------------------------------------------------------------------
// Node kernel, fast path: 2-slab + 3-deep-reg pipeline, 13 slabs,
// one 64-row tile per block, LN epilogue from registers.  (R13, unchanged.)
// ---------------------------------------------------------------------------
__global__ void __launch_bounds__(256, 4)
node_fast(const _Float16* __restrict__ h16, const float* __restrict__ agg,
          const float* __restrict__ h,
          const int* __restrict__ ncol, const int* __restrict__ nrole,
          const float* __restrict__ role_emb, const float* __restrict__ col_emb,
          const _Float16* __restrict__ nwf,   // [13][4096]
          const float* __restrict__ nb1, const float* __restrict__ nb2,
          const float* __restrict__ ln_g, const float* __restrict__ ln_b,
          float* __restrict__ out, int N)
{
    __shared__ __align__(16) _Float16 sB[2 * 4096];
    __shared__ __align__(16) _Float16 sY[64 * 136];
    __shared__ int sRole[64], sCol[64];
    __shared__ float sRoleE[48], sColE[24];

    const int tid  = threadIdx.x;
    const int lane = tid & 63;
    const int wv   = tid >> 6;
    const int lm   = lane & 15;
    const int lh   = lane >> 4;
    const int n0   = blockIdx.x * 64;
    const int r0   = wv * 16 + lm;
    const _Float16* wp = nwf + tid * 16;

    if (tid < 48) sRoleE[tid] = role_emb[tid];
    if (tid < 24) sColE[tid] = col_emb[tid];
    if (tid < 64) {
        int n = n0 + tid; if (n >= N) n = N - 1;
        sRole[tid] = nrole[n];
        sCol[tid]  = ncol[n];
    }

    half8 a[8];
    {
        int n = n0 + r0; if (n >= N) n = N - 1;
        const _Float16* hp = h16 + (size_t)n * H + lh * 8;
        #pragma unroll
        for (int s = 0; s < 4; s++) a[s] = *(const half8*)(hp + s * 32);
        const float* ap = agg + (size_t)n * H + lh * 8;
        #pragma unroll
        for (int s = 0; s < 4; s++) {
            float4 x = *(const float4*)(ap + s * 32);
            float4 y = *(const float4*)(ap + s * 32 + 4);
            a[4 + s] = cvt8(x, y);
        }
    }

    half8 pfa[3], pfb[3];
    {
        half8 s0a = *(const half8*)(wp);
        half8 s0b = *(const half8*)(wp + 8);
        *(half8*)&sB[tid * 16]     = s0a;
        *(half8*)&sB[tid * 16 + 8] = s0b;
        pfa[1] = *(const half8*)(wp + 1 * 4096);
        pfb[1] = *(const half8*)(wp + 1 * 4096 + 8);
        pfa[2] = *(const half8*)(wp + 2 * 4096);
        pfb[2] = *(const half8*)(wp + 2 * 4096 + 8);
    }

    floatx4 acc[8];
    #pragma unroll
    for (int f = 0; f < 8; f++) acc[f] = (floatx4){0.f, 0.f, 0.f, 0.f};

    __syncthreads();

    #pragma unroll
    for (int s = 0; s < 9; s++) {
        if (s + 3 <= 12) {
            pfa[s % 3] = *(const half8*)(wp + (s + 3) * 4096);
            pfb[s % 3] = *(const half8*)(wp + (s + 3) * 4096 + 8);
        }
        half8 af;
        if (s < 8) {
            af = a[s];
        } else {
            if (lh < 2) {
                const float* p = (lh == 0) ? &sRoleE[sRole[r0] * 8] : &sColE[sCol[r0] * 8];
                #pragma unroll
                for (int j = 0; j < 8; j++) af[j] = (_Float16)p[j];
            } else {
                #pragma unroll
                for (int j = 0; j < 8; j++) af[j] = (_Float16)0.0f;
            }
        }
        #pragma unroll
        for (int f = 0; f < 8; f++) {
            half8 bf = *(const half8*)&sB[(s & 1) * 4096 + (f * 64 + lane) * 8];
            acc[f] = __builtin_amdgcn_mfma_f32_16x16x32_f16(af, bf, acc[f], 0, 0, 0);
        }
        {
            _Float16* wdst = &sB[((s + 1) & 1) * 4096 + tid * 16];
            *(half8*)(wdst)     = pfa[(s + 1) % 3];
            *(half8*)(wdst + 8) = pfb[(s + 1) % 3];
        }
        __syncthreads();
    }

    #pragma unroll
    for (int f = 0; f < 8; f++) {
        const int col = f * 16 + lm;
        const float b1 = nb1[col];
        #pragma unroll
        for (int v = 0; v < 4; v++) {
            const int row = wv * 16 + lh * 4 + v;
            sY[row * 136 + col] = (_Float16)silu_f(acc[f][v] + b1);
        }
    }
    asm volatile("s_waitcnt lgkmcnt(0)" ::: "memory");

    floatx4 acc2[8];
    #pragma unroll
    for (int f = 0; f < 8; f++) acc2[f] = (floatx4){0.f, 0.f, 0.f, 0.f};

    #pragma unroll
    for (int s2 = 0; s2 < 4; s2++) {
        const int s = 9 + s2;
        if (s + 3 <= 12) {
            pfa[s % 3] = *(const half8*)(wp + (s + 3) * 4096);
            pfb[s % 3] = *(const half8*)(wp + (s + 3) * 4096 + 8);
        }
        half8 af = *(const half8*)&sY[r0 * 136 + s2 * 32 + lh * 8];
        #pragma unroll
        for (int f = 0; f < 8; f++) {
            half8 bf = *(const half8*)&sB[(s & 1) * 4096 + (f * 64 + lane) * 8];
            acc2[f] = __builtin_amdgcn_mfma_f32_16x16x32_f16(af, bf, acc2[f], 0, 0, 0);
        }
        if (s <= 11) {
            _Float16* wdst = &sB[((s + 1) & 1) * 4096 + tid * 16];
            *(half8*)(wdst)     = pfa[(s + 1) % 3];
            *(half8*)(wdst + 8) = pfb[(s + 1) % 3];
        }
        if (s2 < 3) __syncthreads();
    }

    float g[8], bb[8], b2[8];
    #pragma unroll
    for (int f = 0; f < 8; f++) {
        const int col = f * 16 + lm;
        g[f]  = ln_g[col];
        bb[f] = ln_b[col];
        b2[f] = nb2[col];
    }
    #pragma unroll
    for (int v = 0; v < 4; v++) {
        const int row = n0 + wv * 16 + lh * 4 + v;
        const int rc  = row < N ? row : N - 1;
        float x[8];
        float sum = 0.0f;
        #pragma unroll
        for (int f = 0; f < 8; f++) {
            const int col = f * 16 + lm;
            x[f] = h[(size_t)rc * H + col] + acc2[f][v] + b2[f];
            sum += x[f];
        }
        sum += __shfl_xor(sum, 1);
        sum += __shfl_xor(sum, 2);
        sum += __shfl_xor(sum, 4);
        sum += __shfl_xor(sum, 8);
        const float mu = sum * (1.0f / 128.0f);
        float vs = 0.0f;
        #pragma unroll
        for (int f = 0; f < 8; f++) { float dx = x[f] - mu; vs += dx * dx; }
        vs += __shfl_xor(vs, 1);
        vs += __shfl_xor(vs, 2);
        vs += __shfl_xor(vs, 4);
        vs += __shfl_xor(vs, 8);
        const float rstd = rsqrtf(vs * (1.0f / 128.0f) + LN_EPS);
        if (row < N) {
            #pragma unroll
            for (int f = 0; f < 8; f++) {
                const int col = f * 16 + lm;
                out[(size_t)row * H + col] = (x[f] - mu) * rstd * g[f] + bb[f];
            }
        }
    }
}

// ---------------------------------------------------------------------------
// Node kernel fallback (reads only d_in / d_ws).
// ---------------------------------------------------------------------------
__global__ void __launch_bounds__(256)
node_mfma(const float* __restrict__ h, const float* __restrict__ agg,
          const int* __restrict__ ncol, const int* __restrict__ nrole,
          const float* __restrict__ role_emb, const float* __restrict__ col_emb,
          const float* __restrict__ nW1, const float* __restrict__ nb1,
          const float* __restrict__ nW2, const float* __restrict__ nb2,
          const float* __restrict__ ln_g, const float* __restrict__ ln_b,
          float* __restrict__ out, int N)
{
    __shared__ _Float16 sA[64 * 40];
    __shared__ _Float16 sB[128 * 40];
    __shared__ _Float16 sY[64 * 136];
    __shared__ int sRole[64], sCol[64];
    __shared__ float sRoleE[48], sColE[24];

    const int tid  = threadIdx.x;
    const int lane = tid & 63;
    const int wv   = tid >> 6;
    const int lm   = lane & 15;
    const int lh   = lane >> 4;
    const int n0   = blockIdx.x * 64;

    if (tid < 48) sRoleE[tid] = role_emb[tid];
    if (tid < 24) sColE[tid] = col_emb[tid];
    if (tid < 64) {
        int n = n0 + tid; if (n >= N) n = N - 1;
        sRole[tid] = nrole[n];
        sCol[tid]  = ncol[n];
    }

    floatx4 acc[8];
    #pragma unroll
    for (int f = 0; f < 8; f++) acc[f] = (floatx4){0.f, 0.f, 0.f, 0.f};

    __syncthreads();

    for (int s = 0; s < 9; s++) {
        const int k0 = s * 32;
        {
            const int r  = tid >> 2;
            const int kq = (tid & 3) * 8;
            const int k  = k0 + kq;
            int n = n0 + r; if (n >= N) n = N - 1;
            float v[8];
            if (k < 128) {
                const float4* p = (const float4*)&h[n * H + k];
                float4 a = p[0], b = p[1];
                v[0]=a.x; v[1]=a.y; v[2]=a.z; v[3]=a.w;
                v[4]=b.x; v[5]=b.y; v[6]=b.z; v[7]=b.w;
            } else if (k < 256) {
                const float4* p = (const float4*)&agg[n * H + (k - 128)];
                float4 a = p[0], b = p[1];
                v[0]=a.x; v[1]=a.y; v[2]=a.z; v[3]=a.w;
                v[4]=b.x; v[5]=b.y; v[6]=b.z; v[7]=b.w;
            } else if (k < 264) {
                const float* p = &sRoleE[sRole[r] * 8 + (k - 256)];
                #pragma unroll
                for (int j = 0; j < 8; j++) v[j] = p[j];
            } else if (k < 272) {
                const float* p = &sColE[sCol[r] * 8 + (k - 264)];
                #pragma unroll
                for (int j = 0; j < 8; j++) v[j] = p[j];
            } else {
                #pragma unroll
                for (int j = 0; j < 8; j++) v[j] = 0.0f;
            }
            half8 o;
            #pragma unroll
            for (int j = 0; j < 8; j++) o[j] = (_Float16)v[j];
            *(half8*)&sA[r * 40 + kq] = o;
        }
        {
            const int n  = tid & 127;
            const int kh = (tid >> 7) * 16;
            #pragma unroll
            for (int i = 0; i < 16; i += 2) {
                const int ka = k0 + kh + i;
                const int kb = ka + 1;
                float wa = (ka < 272) ? nW1[ka * H + n] : 0.0f;
                float wb = (kb < 272) ? nW1[kb * H + n] : 0.0f;
                union { _Float16 f[2]; unsigned u; } pk;
                pk.f[0] = (_Float16)wa; pk.f[1] = (_Float16)wb;
                *(unsigned*)&sB[n * 40 + kh + i] = pk.u;
            }
        }
        __syncthreads();
        half8 af = *(const half8*)&sA[(wv * 16 + lm) * 40 + lh * 8];
        #pragma unroll
        for (int f = 0; f < 8; f++) {
            half8 bf = *(const half8*)&sB[(f * 16 + lm) * 40 + lh * 8];
            acc[f] = __builtin_amdgcn_mfma_f32_16x16x32_f16(af, bf, acc[f], 0, 0, 0);
        }
        __syncthreads();
    }

    #pragma unroll
    for (int f = 0; f < 8; f++) {
        const int col = f * 16 + lm;
        const float b1 = nb1[col];
        #pragma unroll
        for (int v = 0; v < 4; v++) {
            const int row = wv * 16 + lh * 4 + v;
            sY[row * 136 + col] = (_Float16)silu_f(acc[f][v] + b1);
        }
    }

    floatx4 acc2[8];
    #pragma unroll
    for (int f = 0; f < 8; f++) acc2[f] = (floatx4){0.f, 0.f, 0.f, 0.f};

    __syncthreads();

    for (int s2 = 0; s2 < 4; s2++) {
        {
            const int n  = tid & 127;
            const int kh = (tid >> 7) * 16;
            #pragma unroll
            for (int i = 0; i < 16; i += 2) {
                const int ka = s2 * 32 + kh + i;
                float wa = nW2[ka * H + n];
                float wb = nW2[(ka + 1) * H + n];
                union { _Float16 f[2]; unsigned u; } pk;
                pk.f[0] = (_Float16)wa; pk.f[1] = (_Float16)wb;
                *(unsigned*)&sB[n * 40 + kh + i] = pk.u;
            }
        }
        __syncthreads();
        half8 af = *(const half8*)&sY[(wv * 16 + lm) * 136 + s2 * 32 + lh * 8];
        #pragma unroll
        for (int f = 0; f < 8; f++) {
            half8 bf = *(const half8*)&sB[(f * 16 + lm) * 40 + lh * 8];
            acc2[f] = __builtin_amdgcn_mfma_f32_16x16x32_f16(af, bf, acc2[f], 0, 0, 0);
        }
        __syncthreads();
    }

    float g[8], bb[8], b2[8];
    #pragma unroll
    for (int f = 0; f < 8; f++) {
        const int col = f * 16 + lm;
        g[f]  = ln_g[col];
        bb[f] = ln_b[col];
        b2[f] = nb2[col];
    }
    #pragma unroll
    for (int v = 0; v < 4; v++) {
        const int row = n0 + wv * 16 + lh * 4 + v;
        const int rc  = row < N ? row : N - 1;
        float x[8];
        float sum = 0.0f;
        #pragma unroll
        for (int f = 0; f < 8; f++) {
            const int col = f * 16 + lm;
            x[f] = h[rc * H + col] + acc2[f][v] + b2[f];
            sum += x[f];
        }
        sum += __shfl_xor(sum, 1);
        sum += __shfl_xor(sum, 2);
        sum += __shfl_xor(sum, 4);
        sum += __shfl_xor(sum, 8);
        const float mu = sum * (1.0f / 128.0f);
        float vs = 0.0f;
        #pragma unroll
        for (int f = 0; f < 8; f++) { float dx = x[f] - mu; vs += dx * dx; }
        vs += __shfl_xor(vs, 1);
        vs += __shfl_xor(vs, 2);
        vs += __shfl_xor(vs, 4);
        vs += __shfl_xor(vs, 8);
        const float rstd = rsqrtf(vs * (1.0f / 128.0f) + LN_EPS);
        if (row < N) {
            #pragma unroll
            for (int f = 0; f < 8; f++) {
                const int col = f * 16 + lm;
                out[row * H + col] = (x[f] - mu) * rstd * g[f] + bb[f];
            }
        }
    }
}

extern "C" void kernel_launch(void* const* d_in, const int* in_sizes, int n_in,
                              void* d_out, int out_size, void* d_ws, size_t ws_size,
                              hipStream_t stream)
{
    const float* h        = (const float*)d_in[0];
    const int*   eidx     = (const int*)d_in[1];
    const int*   erel     = (const int*)d_in[2];
    const int*   ncol     = (const int*)d_in[3];
    const int*   nrole    = (const int*)d_in[4];
    const float* rel_emb  = (const float*)d_in[5];
    const float* role_emb = (const float*)d_in[6];
    const float* col_emb  = (const float*)d_in[7];
    const float* eW1      = (const float*)d_in[8];
    const float* eb1      = (const float*)d_in[9];
    const float* eW2      = (const float*)d_in[10];
    const float* eb2      = (const float*)d_in[11];
    const float* nW1      = (const float*)d_in[12];
    const float* nb1      = (const float*)d_in[13];
    const float* nW2      = (const float*)d_in[14];
    const float* nb2      = (const float*)d_in[15];
    const float* ln_g     = (const float*)d_in[16];
    const float* ln_b     = (const float*)d_in[17];

    const int N = in_sizes[0] / H;
    const int E = in_sizes[2];
    const int* esrc = eidx;
    const int* edst = eidx + E;
    const int bsz = (N + 7) / 8;

    float* agg = (float*)d_ws;

    // Sort scratch in d_out (dead before the node kernel writes out).
    int* perm   = (int*)d_out;
    int* cnt    = perm + E;
    int* base   = cnt + N;
    int* cursor = base + N;
    int* binfo  = cursor + N;

    size_t aggB   = (size_t)N * H * sizeof(float);
    size_t needWs = aggB + (size_t)N * H * 2 + (14 + 13) * 4096 * 2;
    const bool fast = (ws_size >= needWs);

    _Float16 *h16, *wef, *nwf;
    if (fast) {
        h16 = (_Float16*)((char*)d_ws + aggB);
        wef = h16 + (size_t)N * H;
        nwf = wef + 14 * 4096;
    } else {
        size_t io = (size_t)(E + 3 * N + 16);
        io = (io + 7) & ~(size_t)7;
        h16 = (_Float16*)(perm + io);
        wef = h16 + (size_t)N * H;
        nwf = wef + 14 * 4096;
    }

    hipMemsetAsync(agg, 0, aggB, stream);
    hipMemsetAsync(cnt, 0, (size_t)N * sizeof(int), stream);

    cvt_h16<<<(N * H / 8 + 255) / 256, 256, 0, stream>>>(h, h16, N * H / 8);
    cvt_weights<<<(27 * 4096 + 255) / 256, 256, 0, stream>>>(eW1, eW2, nW1, nW2, wef, nwf);

    hist2_kernel<<<512, 256, 0, stream>>>(edst, E, cnt);
    scan2_kernel<<<1, 1024, 0, stream>>>(cnt, base, cursor, N);
    binfo_kernel<<<1, 64, 0, stream>>>(base, N, bsz, E, binfo);
    scatter2_kernel<<<512, 256, 0, stream>>>(edst, E, cursor, perm);

    dim3 egrid(8, 128);
    edge_mfma<<<egrid, 256, 0, stream>>>(
        h16, perm, binfo, esrc, edst, erel, ncol, nrole,
        rel_emb, role_emb, col_emb, wef, eb1, eb2, agg);

    if (fast) {
        node_fast<<<(N + 63) / 64, 256, 0, stream>>>(
            h16, agg, h, ncol, nrole, role_emb, col_emb,
            nwf, nb1, nb2, ln_g, ln_b, (float*)d_out, N);
    } else {
        node_mfma<<<(N + 63) / 64, 256, 0, stream>>>(
            h, agg, ncol, nrole, role_emb, col_emb,
            nW1, nb1, nW2, nb2, ln_g, ln_b, (float*)d_out, N);
    }
}

// Round 16
// 440.292 us; speedup vs baseline: 1.2239x; 1.2239x over previous
//
#include <hip/hip_runtime.h>

#define H 128
#define LN_EPS 1e-5f

typedef _Float16 half8 __attribute__((ext_vector_type(8)));
typedef float floatx4 __attribute__((ext_vector_type(4)));

__device__ __forceinline__ float silu_f(float x) { return x / (1.0f + __expf(-x)); }

// LDS-only barrier: waits ds-ops, leaves global loads in flight (no vmcnt drain).
__device__ __forceinline__ void lgkm_barrier() {
    asm volatile("s_waitcnt lgkmcnt(0)" ::: "memory");
    __builtin_amdgcn_s_barrier();
    __builtin_amdgcn_sched_barrier(0);
}

__device__ __forceinline__ half8 cvt8(float4 a, float4 b) {
    half8 o;
    o[0] = (_Float16)a.x; o[1] = (_Float16)a.y; o[2] = (_Float16)a.z; o[3] = (_Float16)a.w;
    o[4] = (_Float16)b.x; o[5] = (_Float16)b.y; o[6] = (_Float16)b.z; o[7] = (_Float16)b.w;
    return o;
}

// ---------------------------------------------------------------------------
// fp32 -> fp16 h table
// ---------------------------------------------------------------------------
__global__ void cvt_h16(const float* __restrict__ src, _Float16* __restrict__ dst,
                        int total8)
{
    int i = blockIdx.x * blockDim.x + threadIdx.x;
    if (i >= total8) return;
    const float4* p = (const float4*)(src + i * 8);
    *(half8*)(dst + i * 8) = cvt8(p[0], p[1]);
}

// All four weight matrices -> fragment-order fp16 slabs.
// wef: 14 slabs (eW1 10 + eW2 4); nwf: 13 slabs (nW1 9 + nW2 4).
// WF[slab][f][lane][j] = W[k = s*32+(lane>>4)*8+j][col = f*16+(lane&15)]
__global__ void cvt_weights(const float* __restrict__ eW1, const float* __restrict__ eW2,
                            const float* __restrict__ nW1, const float* __restrict__ nW2,
                            _Float16* __restrict__ wef, _Float16* __restrict__ nwf)
{
    int i = blockIdx.x * blockDim.x + threadIdx.x;
    if (i >= 27 * 4096) return;
    int j    = i & 7;
    int lane = (i >> 3) & 63;
    int f    = (i >> 9) & 7;
    int slab = i >> 12;
    int col  = f * 16 + (lane & 15);
    int kin  = (lane >> 4) * 8 + j;
    const float* W; int K, s; _Float16* dst; int di;
    if (slab < 10)      { W = eW1; K = 304; s = slab;      dst = wef; di = i; }
    else if (slab < 14) { W = eW2; K = 128; s = slab - 10; dst = wef; di = i; }
    else if (slab < 23) { W = nW1; K = 272; s = slab - 14; dst = nwf; di = i - 14 * 4096; }
    else                { W = nW2; K = 128; s = slab - 23; dst = nwf; di = i - 14 * 4096; }
    int k = s * 32 + kin;
    dst[di] = (k < K) ? (_Float16)W[k * H + col] : (_Float16)0.0f;
}

// ---------------------------------------------------------------------------
// Full counting sort by dst (N bins).
// ---------------------------------------------------------------------------
__global__ void hist2_kernel(const int* __restrict__ edst, int E,
                             int* __restrict__ cnt)
{
    for (int e = blockIdx.x * blockDim.x + threadIdx.x; e < E;
         e += gridDim.x * blockDim.x)
        atomicAdd(&cnt[edst[e]], 1);
}

__global__ void __launch_bounds__(1024)
scan2_kernel(const int* __restrict__ cnt, int* __restrict__ base,
             int* __restrict__ cursor, int N)
{
    __shared__ int wsum[16];
    __shared__ int woff[16];
    const int tid  = threadIdx.x;
    const int lane = tid & 63;
    const int w    = tid >> 6;
    const int chunk = (N + 1023) >> 10;
    const int lo = min(tid * chunk, N);
    const int hi = min(lo + chunk, N);
    int s = 0;
    for (int i = lo; i < hi; i++) s += cnt[i];
    int v = s;
    #pragma unroll
    for (int d = 1; d < 64; d <<= 1) {
        int u = __shfl_up(v, d);
        if (lane >= d) v += u;
    }
    if (lane == 63) wsum[w] = v;
    __syncthreads();
    if (tid == 0) {
        int r = 0;
        #pragma unroll
        for (int i = 0; i < 16; i++) { int c = wsum[i]; woff[i] = r; r += c; }
    }
    __syncthreads();
    int run = woff[w] + (v - s);
    for (int i = lo; i < hi; i++) {
        base[i] = run; cursor[i] = run;
        run += cnt[i];
    }
}

__global__ void binfo_kernel(const int* __restrict__ base, int N, int bsz, int E,
                             int* __restrict__ binfo)
{
    int b = threadIdx.x;
    if (b < 8) {
        int lo = min(b * bsz, N);
        int hi = min((b + 1) * bsz, N);
        int blo = (lo >= N) ? E : base[lo];
        int bhi = (hi >= N) ? E : base[hi];
        binfo[8 + b] = blo;
        binfo[b]     = bhi - blo;
    }
}

__global__ void scatter2_kernel(const int* __restrict__ edst, int E,
                                int* __restrict__ cursor, int* __restrict__ perm)
{
    for (int e = blockIdx.x * blockDim.x + threadIdx.x; e < E;
         e += gridDim.x * blockDim.x) {
        int p = atomicAdd(&cursor[edst[e]], 1);
        perm[p] = e;
    }
}

// ---------------------------------------------------------------------------
// Edge kernel (R13 structure): 64-edge tiles, dst-sorted; 2-slab LDS B dbuf +
// 3-deep register prefetch.  ALL intra-tile barriers are raw s_barrier with
// lgkmcnt-only waits, so global prefetch/gather loads stay in flight across
// barriers (counted vmcnt at use).  3 blocks/CU for L2 gather locality.
// ---------------------------------------------------------------------------
__global__ void __launch_bounds__(256, 3)
edge_mfma(const _Float16* __restrict__ h16,
          const int* __restrict__ perm, const int* __restrict__ binfo,
          const int* __restrict__ esrc, const int* __restrict__ edst,
          const int* __restrict__ erel, const int* __restrict__ ncol,
          const int* __restrict__ nrole,
          const float* __restrict__ rel_emb, const float* __restrict__ role_emb,
          const float* __restrict__ col_emb,
          const _Float16* __restrict__ wef,   // [14][4096] fragment-order
          const float* __restrict__ eb1, const float* __restrict__ eb2,
          float* __restrict__ agg)
{
    __shared__ __align__(16) unsigned char uR[16896];  // sB 2x8KB / M [32][132] f32
    __shared__ __align__(16) _Float16 sY[64 * 136];
    __shared__ int sSrc[64], sDst[64], sRel[64], sRS[64], sRD[64], sCS[64], sCD[64];
    __shared__ float sRelE[128], sRoleE[48], sColE[24];

    _Float16* sB = (_Float16*)uR;
    float*    M  = (float*)uR;

    const int tid  = threadIdx.x;
    const int lane = tid & 63;
    const int wv   = tid >> 6;
    const int lm   = lane & 15;
    const int lh   = lane >> 4;

    if (tid < 128) sRelE[tid] = rel_emb[tid];
    if (tid < 48)  sRoleE[tid] = role_emb[tid];
    if (tid < 24)  sColE[tid] = col_emb[tid];

    const int bucket = blockIdx.x;
    const int bcount = binfo[bucket];
    const int bbase  = binfo[8 + bucket];

    const int r0 = wv * 16 + lm;          // this lane's A row
    const _Float16* wp = wef + tid * 16;

    float bias1[8], bias2[8];
    #pragma unroll
    for (int f = 0; f < 8; f++) { bias1[f] = eb1[f * 16 + lm]; bias2[f] = eb2[f * 16 + lm]; }

    for (int t = blockIdx.y; t * 64 < bcount; t += gridDim.y)
    {
        lgkm_barrier();   // previous tile's LDS (M, sB, sDst) fully consumed

        if (tid < 64) {
            int idx   = t * 64 + tid;
            int valid = idx < bcount;
            int e = valid ? perm[bbase + idx] : perm[bbase];
            int s = esrc[e], d = edst[e], r = erel[e];
            sSrc[tid] = s; sRel[tid] = r;
            sRS[tid]  = nrole[s]; sRD[tid] = nrole[d];
            sCS[tid]  = ncol[s];  sCD[tid] = ncol[d];
            sDst[tid] = valid ? d : -1;
        }
        lgkm_barrier();

        // ---- A-fragments: 8 direct global loads into registers ----
        half8 a[8];
        {
            const int asrc = sSrc[r0];
            int adst = sDst[r0]; if (adst < 0) adst = asrc;
            const _Float16* sp = &h16[(size_t)asrc * H + lh * 8];
            const _Float16* dp = &h16[(size_t)adst * H + lh * 8];
            #pragma unroll
            for (int s = 0; s < 4; s++) a[s]     = *(const half8*)(sp + s * 32);
            #pragma unroll
            for (int s = 0; s < 4; s++) a[4 + s] = *(const half8*)(dp + s * 32);
        }

        // ---- B prologue: slab 0 -> LDS slot 0; slabs 1,2 -> pf regs ----
        half8 pfa[3], pfb[3];
        {
            half8 s0a = *(const half8*)(wp);
            half8 s0b = *(const half8*)(wp + 8);
            *(half8*)&sB[tid * 16]     = s0a;
            *(half8*)&sB[tid * 16 + 8] = s0b;
            pfa[1] = *(const half8*)(wp + 1 * 4096);
            pfb[1] = *(const half8*)(wp + 1 * 4096 + 8);
            pfa[2] = *(const half8*)(wp + 2 * 4096);
            pfb[2] = *(const half8*)(wp + 2 * 4096 + 8);
        }

        floatx4 acc[8];
        #pragma unroll
        for (int f = 0; f < 8; f++) acc[f] = (floatx4){0.f, 0.f, 0.f, 0.f};

        lgkm_barrier();   // slab0 + meta visible

        // ---- MLP1: steps 0..9 ----
        #pragma unroll
        for (int s = 0; s < 10; s++) {
            if (s + 3 <= 13) {
                pfa[s % 3] = *(const half8*)(wp + (s + 3) * 4096);
                pfb[s % 3] = *(const half8*)(wp + (s + 3) * 4096 + 8);
            }
            half8 af;
            if (s < 8) {
                af = a[s];
            } else if (s == 8) {
                const float* p = (lh == 0) ? &sRelE[sRel[r0] * 16]
                               : (lh == 1) ? &sRelE[sRel[r0] * 16 + 8]
                               : (lh == 2) ? &sRoleE[sRS[r0] * 8]
                                           : &sRoleE[sRD[r0] * 8];
                #pragma unroll
                for (int j = 0; j < 8; j++) af[j] = (_Float16)p[j];
            } else {
                if (lh < 2) {
                    const float* p = (lh == 0) ? &sColE[sCS[r0] * 8] : &sColE[sCD[r0] * 8];
                    #pragma unroll
                    for (int j = 0; j < 8; j++) af[j] = (_Float16)p[j];
                } else {
                    #pragma unroll
                    for (int j = 0; j < 8; j++) af[j] = (_Float16)0.0f;
                }
            }
            #pragma unroll
            for (int f = 0; f < 8; f++) {
                half8 bf = *(const half8*)&sB[(s & 1) * 4096 + (f * 64 + lane) * 8];
                acc[f] = __builtin_amdgcn_mfma_f32_16x16x32_f16(af, bf, acc[f], 0, 0, 0);
            }
            {
                _Float16* wdst = &sB[((s + 1) & 1) * 4096 + tid * 16];
                *(half8*)(wdst)     = pfa[(s + 1) % 3];
                *(half8*)(wdst + 8) = pfb[(s + 1) % 3];
            }
            lgkm_barrier();
        }

        // ---- transition (wave-local rows): sY = silu(acc + eb1) ----
        #pragma unroll
        for (int f = 0; f < 8; f++) {
            const int col = f * 16 + lm;
            #pragma unroll
            for (int v = 0; v < 4; v++) {
                const int row = wv * 16 + lh * 4 + v;
                sY[row * 136 + col] = (_Float16)silu_f(acc[f][v] + bias1[f]);
            }
        }
        asm volatile("s_waitcnt lgkmcnt(0)" ::: "memory");
        __builtin_amdgcn_sched_barrier(0);

        floatx4 acc2[8];
        #pragma unroll
        for (int f = 0; f < 8; f++) acc2[f] = (floatx4){0.f, 0.f, 0.f, 0.f};

        // ---- MLP2: steps 10..13 ----
        #pragma unroll
        for (int s2 = 0; s2 < 4; s2++) {
            const int s = 10 + s2;
            if (s + 3 <= 13) {   // s == 10 only
                pfa[s % 3] = *(const half8*)(wp + (s + 3) * 4096);
                pfb[s % 3] = *(const half8*)(wp + (s + 3) * 4096 + 8);
            }
            half8 af = *(const half8*)&sY[r0 * 136 + s2 * 32 + lh * 8];
            #pragma unroll
            for (int f = 0; f < 8; f++) {
                half8 bf = *(const half8*)&sB[(s & 1) * 4096 + (f * 64 + lane) * 8];
                acc2[f] = __builtin_amdgcn_mfma_f32_16x16x32_f16(af, bf, acc2[f], 0, 0, 0);
            }
            if (s <= 12) {
                _Float16* wdst = &sB[((s + 1) & 1) * 4096 + tid * 16];
                *(half8*)(wdst)     = pfa[(s + 1) % 3];
                *(half8*)(wdst + 8) = pfb[(s + 1) % 3];
            }
            if (s2 < 3) lgkm_barrier();
        }

        // ---- epilogue: 2 passes; bulk-load regs then run-length atomics ----
        #pragma unroll
        for (int p = 0; p < 2; p++) {
            lgkm_barrier();   // sB reads (and previous M reads) complete
            if ((wv >> 1) == p) {
                #pragma unroll
                for (int f = 0; f < 8; f++) {
                    const int col = f * 16 + lm;
                    #pragma unroll
                    for (int v = 0; v < 4; v++) {
                        const int row = wv * 16 + lh * 4 + v;
                        M[(row & 31) * 132 + col] = silu_f(acc2[f][v] + bias2[f]);
                    }
                }
            }
            lgkm_barrier();
            {
                const int c  = tid & 127;
                const int rb = (tid >> 7) * 16;
                float m[16]; int dd[16];
                #pragma unroll
                for (int i = 0; i < 16; i++) {
                    m[i]  = M[(rb + i) * 132 + c];
                    dd[i] = sDst[p * 32 + rb + i];
                }
                float acz = 0.0f; int cur = -1;
                #pragma unroll
                for (int i = 0; i < 16; i++) {
                    if (dd[i] != cur) {
                        if (cur >= 0) unsafeAtomicAdd(&agg[cur * H + c], acz);
                        acz = 0.0f; cur = dd[i];
                    }
                    if (dd[i] >= 0) acz += m[i];
                }
                if (cur >= 0) unsafeAtomicAdd(&agg[cur * H + c], acz);
            }
        }
    }
}

// ---------------------------------------------------------------------------
// Node kernel, fast path: 2-slab + 3-deep-reg pipeline, 13 slabs, raw lgkm
// barriers, one 64-row tile per block, LN epilogue from registers.
// ---------------------------------------------------------------------------
__global__ void __launch_bounds__(256, 4)
node_fast(const _Float16* __restrict__ h16, const float* __restrict__ agg,
          const float* __restrict__ h,
          const int* __restrict__ ncol, const int* __restrict__ nrole,
          const float* __restrict__ role_emb, const float* __restrict__ col_emb,
          const _Float16* __restrict__ nwf,   // [13][4096]
          const float* __restrict__ nb1, const float* __restrict__ nb2,
          const float* __restrict__ ln_g, const float* __restrict__ ln_b,
          float* __restrict__ out, int N)
{
    __shared__ __align__(16) _Float16 sB[2 * 4096];
    __shared__ __align__(16) _Float16 sY[64 * 136];
    __shared__ int sRole[64], sCol[64];
    __shared__ float sRoleE[48], sColE[24];

    const int tid  = threadIdx.x;
    const int lane = tid & 63;
    const int wv   = tid >> 6;
    const int lm   = lane & 15;
    const int lh   = lane >> 4;
    const int n0   = blockIdx.x * 64;
    const int r0   = wv * 16 + lm;
    const _Float16* wp = nwf + tid * 16;

    if (tid < 48) sRoleE[tid] = role_emb[tid];
    if (tid < 24) sColE[tid] = col_emb[tid];
    if (tid < 64) {
        int n = n0 + tid; if (n >= N) n = N - 1;
        sRole[tid] = nrole[n];
        sCol[tid]  = ncol[n];
    }

    half8 a[8];
    {
        int n = n0 + r0; if (n >= N) n = N - 1;
        const _Float16* hp = h16 + (size_t)n * H + lh * 8;
        #pragma unroll
        for (int s = 0; s < 4; s++) a[s] = *(const half8*)(hp + s * 32);
        const float* ap = agg + (size_t)n * H + lh * 8;
        #pragma unroll
        for (int s = 0; s < 4; s++) {
            float4 x = *(const float4*)(ap + s * 32);
            float4 y = *(const float4*)(ap + s * 32 + 4);
            a[4 + s] = cvt8(x, y);
        }
    }

    half8 pfa[3], pfb[3];
    {
        half8 s0a = *(const half8*)(wp);
        half8 s0b = *(const half8*)(wp + 8);
        *(half8*)&sB[tid * 16]     = s0a;
        *(half8*)&sB[tid * 16 + 8] = s0b;
        pfa[1] = *(const half8*)(wp + 1 * 4096);
        pfb[1] = *(const half8*)(wp + 1 * 4096 + 8);
        pfa[2] = *(const half8*)(wp + 2 * 4096);
        pfb[2] = *(const half8*)(wp + 2 * 4096 + 8);
    }

    floatx4 acc[8];
    #pragma unroll
    for (int f = 0; f < 8; f++) acc[f] = (floatx4){0.f, 0.f, 0.f, 0.f};

    lgkm_barrier();

    #pragma unroll
    for (int s = 0; s < 9; s++) {
        if (s + 3 <= 12) {
            pfa[s % 3] = *(const half8*)(wp + (s + 3) * 4096);
            pfb[s % 3] = *(const half8*)(wp + (s + 3) * 4096 + 8);
        }
        half8 af;
        if (s < 8) {
            af = a[s];
        } else {
            if (lh < 2) {
                const float* p = (lh == 0) ? &sRoleE[sRole[r0] * 8] : &sColE[sCol[r0] * 8];
                #pragma unroll
                for (int j = 0; j < 8; j++) af[j] = (_Float16)p[j];
            } else {
                #pragma unroll
                for (int j = 0; j < 8; j++) af[j] = (_Float16)0.0f;
            }
        }
        #pragma unroll
        for (int f = 0; f < 8; f++) {
            half8 bf = *(const half8*)&sB[(s & 1) * 4096 + (f * 64 + lane) * 8];
            acc[f] = __builtin_amdgcn_mfma_f32_16x16x32_f16(af, bf, acc[f], 0, 0, 0);
        }
        {
            _Float16* wdst = &sB[((s + 1) & 1) * 4096 + tid * 16];
            *(half8*)(wdst)     = pfa[(s + 1) % 3];
            *(half8*)(wdst + 8) = pfb[(s + 1) % 3];
        }
        lgkm_barrier();
    }

    #pragma unroll
    for (int f = 0; f < 8; f++) {
        const int col = f * 16 + lm;
        const float b1 = nb1[col];
        #pragma unroll
        for (int v = 0; v < 4; v++) {
            const int row = wv * 16 + lh * 4 + v;
            sY[row * 136 + col] = (_Float16)silu_f(acc[f][v] + b1);
        }
    }
    asm volatile("s_waitcnt lgkmcnt(0)" ::: "memory");
    __builtin_amdgcn_sched_barrier(0);

    floatx4 acc2[8];
    #pragma unroll
    for (int f = 0; f < 8; f++) acc2[f] = (floatx4){0.f, 0.f, 0.f, 0.f};

    #pragma unroll
    for (int s2 = 0; s2 < 4; s2++) {
        const int s = 9 + s2;
        if (s + 3 <= 12) {
            pfa[s % 3] = *(const half8*)(wp + (s + 3) * 4096);
            pfb[s % 3] = *(const half8*)(wp + (s + 3) * 4096 + 8);
        }
        half8 af = *(const half8*)&sY[r0 * 136 + s2 * 32 + lh * 8];
        #pragma unroll
        for (int f = 0; f < 8; f++) {
            half8 bf = *(const half8*)&sB[(s & 1) * 4096 + (f * 64 + lane) * 8];
            acc2[f] = __builtin_amdgcn_mfma_f32_16x16x32_f16(af, bf, acc2[f], 0, 0, 0);
        }
        if (s <= 11) {
            _Float16* wdst = &sB[((s + 1) & 1) * 4096 + tid * 16];
            *(half8*)(wdst)     = pfa[(s + 1) % 3];
            *(half8*)(wdst + 8) = pfb[(s + 1) % 3];
        }
        if (s2 < 3) lgkm_barrier();
    }

    float g[8], bb[8], b2[8];
    #pragma unroll
    for (int f = 0; f < 8; f++) {
        const int col = f * 16 + lm;
        g[f]  = ln_g[col];
        bb[f] = ln_b[col];
        b2[f] = nb2[col];
    }
    #pragma unroll
    for (int v = 0; v < 4; v++) {
        const int row = n0 + wv * 16 + lh * 4 + v;
        const int rc  = row < N ? row : N - 1;
        float x[8];
        float sum = 0.0f;
        #pragma unroll
        for (int f = 0; f < 8; f++) {
            const int col = f * 16 + lm;
            x[f] = h[(size_t)rc * H + col] + acc2[f][v] + b2[f];
            sum += x[f];
        }
        sum += __shfl_xor(sum, 1);
        sum += __shfl_xor(sum, 2);
        sum += __shfl_xor(sum, 4);
        sum += __shfl_xor(sum, 8);
        const float mu = sum * (1.0f / 128.0f);
        float vs = 0.0f;
        #pragma unroll
        for (int f = 0; f < 8; f++) { float dx = x[f] - mu; vs += dx * dx; }
        vs += __shfl_xor(vs, 1);
        vs += __shfl_xor(vs, 2);
        vs += __shfl_xor(vs, 4);
        vs += __shfl_xor(vs, 8);
        const float rstd = rsqrtf(vs * (1.0f / 128.0f) + LN_EPS);
        if (row < N) {
            #pragma unroll
            for (int f = 0; f < 8; f++) {
                const int col = f * 16 + lm;
                out[(size_t)row * H + col] = (x[f] - mu) * rstd * g[f] + bb[f];
            }
        }
    }
}

// ---------------------------------------------------------------------------
// Node kernel fallback (reads only d_in / d_ws).
// ---------------------------------------------------------------------------
__global__ void __launch_bounds__(256)
node_mfma(const float* __restrict__ h, const float* __restrict__ agg,
          const int* __restrict__ ncol, const int* __restrict__ nrole,
          const float* __restrict__ role_emb, const float* __restrict__ col_emb,
          const float* __restrict__ nW1, const float* __restrict__ nb1,
          const float* __restrict__ nW2, const float* __restrict__ nb2,
          const float* __restrict__ ln_g, const float* __restrict__ ln_b,
          float* __restrict__ out, int N)
{
    __shared__ _Float16 sA[64 * 40];
    __shared__ _Float16 sB[128 * 40];
    __shared__ _Float16 sY[64 * 136];
    __shared__ int sRole[64], sCol[64];
    __shared__ float sRoleE[48], sColE[24];

    const int tid  = threadIdx.x;
    const int lane = tid & 63;
    const int wv   = tid >> 6;
    const int lm   = lane & 15;
    const int lh   = lane >> 4;
    const int n0   = blockIdx.x * 64;

    if (tid < 48) sRoleE[tid] = role_emb[tid];
    if (tid < 24) sColE[tid] = col_emb[tid];
    if (tid < 64) {
        int n = n0 + tid; if (n >= N) n = N - 1;
        sRole[tid] = nrole[n];
        sCol[tid]  = ncol[n];
    }

    floatx4 acc[8];
    #pragma unroll
    for (int f = 0; f < 8; f++) acc[f] = (floatx4){0.f, 0.f, 0.f, 0.f};

    __syncthreads();

    for (int s = 0; s < 9; s++) {
        const int k0 = s * 32;
        {
            const int r  = tid >> 2;
            const int kq = (tid & 3) * 8;
            const int k  = k0 + kq;
            int n = n0 + r; if (n >= N) n = N - 1;
            float v[8];
            if (k < 128) {
                const float4* p = (const float4*)&h[n * H + k];
                float4 a = p[0], b = p[1];
                v[0]=a.x; v[1]=a.y; v[2]=a.z; v[3]=a.w;
                v[4]=b.x; v[5]=b.y; v[6]=b.z; v[7]=b.w;
            } else if (k < 256) {
                const float4* p = (const float4*)&agg[n * H + (k - 128)];
                float4 a = p[0], b = p[1];
                v[0]=a.x; v[1]=a.y; v[2]=a.z; v[3]=a.w;
                v[4]=b.x; v[5]=b.y; v[6]=b.z; v[7]=b.w;
            } else if (k < 264) {
                const float* p = &sRoleE[sRole[r] * 8 + (k - 256)];
                #pragma unroll
                for (int j = 0; j < 8; j++) v[j] = p[j];
            } else if (k < 272) {
                const float* p = &sColE[sCol[r] * 8 + (k - 264)];
                #pragma unroll
                for (int j = 0; j < 8; j++) v[j] = p[j];
            } else {
                #pragma unroll
                for (int j = 0; j < 8; j++) v[j] = 0.0f;
            }
            half8 o;
            #pragma unroll
            for (int j = 0; j < 8; j++) o[j] = (_Float16)v[j];
            *(half8*)&sA[r * 40 + kq] = o;
        }
        {
            const int n  = tid & 127;
            const int kh = (tid >> 7) * 16;
            #pragma unroll
            for (int i = 0; i < 16; i += 2) {
                const int ka = k0 + kh + i;
                const int kb = ka + 1;
                float wa = (ka < 272) ? nW1[ka * H + n] : 0.0f;
                float wb = (kb < 272) ? nW1[kb * H + n] : 0.0f;
                union { _Float16 f[2]; unsigned u; } pk;
                pk.f[0] = (_Float16)wa; pk.f[1] = (_Float16)wb;
                *(unsigned*)&sB[n * 40 + kh + i] = pk.u;
            }
        }
        __syncthreads();
        half8 af = *(const half8*)&sA[(wv * 16 + lm) * 40 + lh * 8];
        #pragma unroll
        for (int f = 0; f < 8; f++) {
            half8 bf = *(const half8*)&sB[(f * 16 + lm) * 40 + lh * 8];
            acc[f] = __builtin_amdgcn_mfma_f32_16x16x32_f16(af, bf, acc[f], 0, 0, 0);
        }
        __syncthreads();
    }

    #pragma unroll
    for (int f = 0; f < 8; f++) {
        const int col = f * 16 + lm;
        const float b1 = nb1[col];
        #pragma unroll
        for (int v = 0; v < 4; v++) {
            const int row = wv * 16 + lh * 4 + v;
            sY[row * 136 + col] = (_Float16)silu_f(acc[f][v] + b1);
        }
    }

    floatx4 acc2[8];
    #pragma unroll
    for (int f = 0; f < 8; f++) acc2[f] = (floatx4){0.f, 0.f, 0.f, 0.f};

    __syncthreads();

    for (int s2 = 0; s2 < 4; s2++) {
        {
            const int n  = tid & 127;
            const int kh = (tid >> 7) * 16;
            #pragma unroll
            for (int i = 0; i < 16; i += 2) {
                const int ka = s2 * 32 + kh + i;
                float wa = nW2[ka * H + n];
                float wb = nW2[(ka + 1) * H + n];
                union { _Float16 f[2]; unsigned u; } pk;
                pk.f[0] = (_Float16)wa; pk.f[1] = (_Float16)wb;
                *(unsigned*)&sB[n * 40 + kh + i] = pk.u;
            }
        }
        __syncthreads();
        half8 af = *(const half8*)&sY[(wv * 16 + lm) * 136 + s2 * 32 + lh * 8];
        #pragma unroll
        for (int f = 0; f < 8; f++) {
            half8 bf = *(const half8*)&sB[(f * 16 + lm) * 40 + lh * 8];
            acc2[f] = __builtin_amdgcn_mfma_f32_16x16x32_f16(af, bf, acc2[f], 0, 0, 0);
        }
        __syncthreads();
    }

    float g[8], bb[8], b2[8];
    #pragma unroll
    for (int f = 0; f < 8; f++) {
        const int col = f * 16 + lm;
        g[f]  = ln_g[col];
        bb[f] = ln_b[col];
        b2[f] = nb2[col];
    }
    #pragma unroll
    for (int v = 0; v < 4; v++) {
        const int row = n0 + wv * 16 + lh * 4 + v;
        const int rc  = row < N ? row : N - 1;
        float x[8];
        float sum = 0.0f;
        #pragma unroll
        for (int f = 0; f < 8; f++) {
            const int col = f * 16 + lm;
            x[f] = h[rc * H + col] + acc2[f][v] + b2[f];
            sum += x[f];
        }
        sum += __shfl_xor(sum, 1);
        sum += __shfl_xor(sum, 2);
        sum += __shfl_xor(sum, 4);
        sum += __shfl_xor(sum, 8);
        const float mu = sum * (1.0f / 128.0f);
        float vs = 0.0f;
        #pragma unroll
        for (int f = 0; f < 8; f++) { float dx = x[f] - mu; vs += dx * dx; }
        vs += __shfl_xor(vs, 1);
        vs += __shfl_xor(vs, 2);
        vs += __shfl_xor(vs, 4);
        vs += __shfl_xor(vs, 8);
        const float rstd = rsqrtf(vs * (1.0f / 128.0f) + LN_EPS);
        if (row < N) {
            #pragma unroll
            for (int f = 0; f < 8; f++) {
                const int col = f * 16 + lm;
                out[row * H + col] = (x[f] - mu) * rstd * g[f] + bb[f];
            }
        }
    }
}

extern "C" void kernel_launch(void* const* d_in, const int* in_sizes, int n_in,
                              void* d_out, int out_size, void* d_ws, size_t ws_size,
                              hipStream_t stream)
{
    const float* h        = (const float*)d_in[0];
    const int*   eidx     = (const int*)d_in[1];
    const int*   erel     = (const int*)d_in[2];
    const int*   ncol     = (const int*)d_in[3];
    const int*   nrole    = (const int*)d_in[4];
    const float* rel_emb  = (const float*)d_in[5];
    const float* role_emb = (const float*)d_in[6];
    const float* col_emb  = (const float*)d_in[7];
    const float* eW1      = (const float*)d_in[8];
    const float* eb1      = (const float*)d_in[9];
    const float* eW2      = (const float*)d_in[10];
    const float* eb2      = (const float*)d_in[11];
    const float* nW1      = (const float*)d_in[12];
    const float* nb1      = (const float*)d_in[13];
    const float* nW2      = (const float*)d_in[14];
    const float* nb2      = (const float*)d_in[15];
    const float* ln_g     = (const float*)d_in[16];
    const float* ln_b     = (const float*)d_in[17];

    const int N = in_sizes[0] / H;
    const int E = in_sizes[2];
    const int* esrc = eidx;
    const int* edst = eidx + E;
    const int bsz = (N + 7) / 8;

    float* agg = (float*)d_ws;

    // Sort scratch in d_out (dead before the node kernel writes out).
    int* perm   = (int*)d_out;
    int* cnt    = perm + E;
    int* base   = cnt + N;
    int* cursor = base + N;
    int* binfo  = cursor + N;

    size_t aggB   = (size_t)N * H * sizeof(float);
    size_t needWs = aggB + (size_t)N * H * 2 + (14 + 13) * 4096 * 2;
    const bool fast = (ws_size >= needWs);

    _Float16 *h16, *wef, *nwf;
    if (fast) {
        h16 = (_Float16*)((char*)d_ws + aggB);
        wef = h16 + (size_t)N * H;
        nwf = wef + 14 * 4096;
    } else {
        size_t io = (size_t)(E + 3 * N + 16);
        io = (io + 7) & ~(size_t)7;
        h16 = (_Float16*)(perm + io);
        wef = h16 + (size_t)N * H;
        nwf = wef + 14 * 4096;
    }

    hipMemsetAsync(agg, 0, aggB, stream);
    hipMemsetAsync(cnt, 0, (size_t)N * sizeof(int), stream);

    cvt_h16<<<(N * H / 8 + 255) / 256, 256, 0, stream>>>(h, h16, N * H / 8);
    cvt_weights<<<(27 * 4096 + 255) / 256, 256, 0, stream>>>(eW1, eW2, nW1, nW2, wef, nwf);

    hist2_kernel<<<512, 256, 0, stream>>>(edst, E, cnt);
    scan2_kernel<<<1, 1024, 0, stream>>>(cnt, base, cursor, N);
    binfo_kernel<<<1, 64, 0, stream>>>(base, N, bsz, E, binfo);
    scatter2_kernel<<<512, 256, 0, stream>>>(edst, E, cursor, perm);

    dim3 egrid(8, 96);
    edge_mfma<<<egrid, 256, 0, stream>>>(
        h16, perm, binfo, esrc, edst, erel, ncol, nrole,
        rel_emb, role_emb, col_emb, wef, eb1, eb2, agg);

    if (fast) {
        node_fast<<<(N + 63) / 64, 256, 0, stream>>>(
            h16, agg, h, ncol, nrole, role_emb, col_emb,
            nwf, nb1, nb2, ln_g, ln_b, (float*)d_out, N);
    } else {
        node_mfma<<<(N + 63) / 64, 256, 0, stream>>>(
            h, agg, ncol, nrole, role_emb, col_emb,
            nW1, nb1, nW2, nb2, ln_g, ln_b, (float*)d_out, N);
    }
}

// Round 17
// 404.226 us; speedup vs baseline: 1.3331x; 1.0892x over previous
//
#include <hip/hip_runtime.h>

#define H 128
#define LN_EPS 1e-5f

typedef _Float16 half8 __attribute__((ext_vector_type(8)));
typedef float floatx4 __attribute__((ext_vector_type(4)));

__device__ __forceinline__ float silu_f(float x) { return x / (1.0f + __expf(-x)); }

// LDS-only barrier: waits ds-ops, leaves global loads in flight (no vmcnt drain).
__device__ __forceinline__ void lgkm_barrier() {
    asm volatile("s_waitcnt lgkmcnt(0)" ::: "memory");
    __builtin_amdgcn_s_barrier();
    __builtin_amdgcn_sched_barrier(0);
}

__device__ __forceinline__ half8 cvt8(float4 a, float4 b) {
    half8 o;
    o[0] = (_Float16)a.x; o[1] = (_Float16)a.y; o[2] = (_Float16)a.z; o[3] = (_Float16)a.w;
    o[4] = (_Float16)b.x; o[5] = (_Float16)b.y; o[6] = (_Float16)b.z; o[7] = (_Float16)b.w;
    return o;
}

// ---------------------------------------------------------------------------
// fp32 -> fp16 h table
// ---------------------------------------------------------------------------
__global__ void cvt_h16(const float* __restrict__ src, _Float16* __restrict__ dst,
                        int total8)
{
    int i = blockIdx.x * blockDim.x + threadIdx.x;
    if (i >= total8) return;
    const float4* p = (const float4*)(src + i * 8);
    *(half8*)(dst + i * 8) = cvt8(p[0], p[1]);
}

// All four weight matrices -> fragment-order fp16 slabs.
// wef: 14 slabs (eW1 10 + eW2 4); nwf: 13 slabs (nW1 9 + nW2 4).
// WF[slab][f][lane][j] = W[k = s*32+(lane>>4)*8+j][col = f*16+(lane&15)]
__global__ void cvt_weights(const float* __restrict__ eW1, const float* __restrict__ eW2,
                            const float* __restrict__ nW1, const float* __restrict__ nW2,
                            _Float16* __restrict__ wef, _Float16* __restrict__ nwf)
{
    int i = blockIdx.x * blockDim.x + threadIdx.x;
    if (i >= 27 * 4096) return;
    int j    = i & 7;
    int lane = (i >> 3) & 63;
    int f    = (i >> 9) & 7;
    int slab = i >> 12;
    int col  = f * 16 + (lane & 15);
    int kin  = (lane >> 4) * 8 + j;
    const float* W; int K, s; _Float16* dst; int di;
    if (slab < 10)      { W = eW1; K = 304; s = slab;      dst = wef; di = i; }
    else if (slab < 14) { W = eW2; K = 128; s = slab - 10; dst = wef; di = i; }
    else if (slab < 23) { W = nW1; K = 272; s = slab - 14; dst = nwf; di = i - 14 * 4096; }
    else                { W = nW2; K = 128; s = slab - 23; dst = nwf; di = i - 14 * 4096; }
    int k = s * 32 + kin;
    dst[di] = (k < K) ? (_Float16)W[k * H + col] : (_Float16)0.0f;
}

// ---------------------------------------------------------------------------
// Full counting sort by dst (N bins).
// ---------------------------------------------------------------------------
__global__ void hist2_kernel(const int* __restrict__ edst, int E,
                             int* __restrict__ cnt)
{
    for (int e = blockIdx.x * blockDim.x + threadIdx.x; e < E;
         e += gridDim.x * blockDim.x)
        atomicAdd(&cnt[edst[e]], 1);
}

__global__ void __launch_bounds__(1024)
scan2_kernel(const int* __restrict__ cnt, int* __restrict__ base,
             int* __restrict__ cursor, int N)
{
    __shared__ int wsum[16];
    __shared__ int woff[16];
    const int tid  = threadIdx.x;
    const int lane = tid & 63;
    const int w    = tid >> 6;
    const int chunk = (N + 1023) >> 10;
    const int lo = min(tid * chunk, N);
    const int hi = min(lo + chunk, N);
    int s = 0;
    for (int i = lo; i < hi; i++) s += cnt[i];
    int v = s;
    #pragma unroll
    for (int d = 1; d < 64; d <<= 1) {
        int u = __shfl_up(v, d);
        if (lane >= d) v += u;
    }
    if (lane == 63) wsum[w] = v;
    __syncthreads();
    if (tid == 0) {
        int r = 0;
        #pragma unroll
        for (int i = 0; i < 16; i++) { int c = wsum[i]; woff[i] = r; r += c; }
    }
    __syncthreads();
    int run = woff[w] + (v - s);
    for (int i = lo; i < hi; i++) {
        base[i] = run; cursor[i] = run;
        run += cnt[i];
    }
}

__global__ void binfo_kernel(const int* __restrict__ base, int N, int bsz, int E,
                             int* __restrict__ binfo)
{
    int b = threadIdx.x;
    if (b < 8) {
        int lo = min(b * bsz, N);
        int hi = min((b + 1) * bsz, N);
        int blo = (lo >= N) ? E : base[lo];
        int bhi = (hi >= N) ? E : base[hi];
        binfo[8 + b] = blo;
        binfo[b]     = bhi - blo;
    }
}

__global__ void scatter2_kernel(const int* __restrict__ edst, int E,
                                int* __restrict__ cursor, int* __restrict__ perm)
{
    for (int e = blockIdx.x * blockDim.x + threadIdx.x; e < E;
         e += gridDim.x * blockDim.x) {
        int p = atomicAdd(&cursor[edst[e]], 1);
        perm[p] = e;
    }
}

// ---------------------------------------------------------------------------
// Edge kernel: 64-edge tiles, dst-sorted.  K=64 macro-steps (7 steps total:
// 5 MLP1 + 2 MLP2) over paired 4096-half slabs; 2x16KB LDS slots with a
// 2-set register prefetch (pair s+2 loaded at step s, written at step s+1 ->
// full-step latency cover).  Per-thread meta in registers (no meta barrier);
// single-pass fp32-M epilogue overlaying dead sB/sY.  ~10 barriers/tile.
// ---------------------------------------------------------------------------
__global__ void __launch_bounds__(256, 3)
edge_mfma(const _Float16* __restrict__ h16,
          const int* __restrict__ perm, const int* __restrict__ binfo,
          const int* __restrict__ esrc, const int* __restrict__ edst,
          const int* __restrict__ erel, const int* __restrict__ ncol,
          const int* __restrict__ nrole,
          const float* __restrict__ rel_emb, const float* __restrict__ role_emb,
          const float* __restrict__ col_emb,
          const _Float16* __restrict__ wef,   // [14][4096] fragment-order
          const float* __restrict__ eb1, const float* __restrict__ eb2,
          float* __restrict__ agg)
{
    // uR: sB 2 slots x 8192 halfs (32768 B) | sY [64][136] fp16 (17408 B)
    //     M fp32 [64][132] (33792 B) overlays the front when sB/sY are dead.
    __shared__ __align__(16) unsigned char uR[50176];
    __shared__ int sDst[64];
    __shared__ float sRelE[128], sRoleE[48], sColE[24];

    _Float16* sB = (_Float16*)uR;               // 2 x 8192 halfs
    _Float16* sY = (_Float16*)(uR + 32768);     // [64][136]
    float*    M  = (float*)uR;                  // [64][132]

    const int tid  = threadIdx.x;
    const int lane = tid & 63;
    const int wv   = tid >> 6;
    const int lm   = lane & 15;
    const int lh   = lane >> 4;

    if (tid < 128) sRelE[tid] = rel_emb[tid];
    if (tid < 48)  sRoleE[tid] = role_emb[tid];
    if (tid < 24)  sColE[tid] = col_emb[tid];

    const int bucket = blockIdx.x;
    const int bcount = binfo[bucket];
    const int bbase  = binfo[8 + bucket];

    const int r0 = wv * 16 + lm;               // this thread's A row
    const _Float16* wp = wef + tid * 16;

    float bias1[8], bias2[8];
    #pragma unroll
    for (int f = 0; f < 8; f++) { bias1[f] = eb1[f * 16 + lm]; bias2[f] = eb2[f * 16 + lm]; }

    for (int t = blockIdx.y; t * 64 < bcount; t += gridDim.y)
    {
        lgkm_barrier();   // prev tile fully consumed (M reads, sDst reads)

        // ---- per-thread meta (redundant x4 per row; L1 broadcast) ----
        const int idx   = t * 64 + r0;
        const int valid = idx < bcount;
        const int e     = perm[bbase + (valid ? idx : 0)];
        const int mSrc  = esrc[e];
        const int d     = edst[e];
        const int mRel  = erel[e];
        const int mRS = nrole[mSrc], mRD = nrole[d];
        const int mCS = ncol[mSrc],  mCD = ncol[d];
        const int mDst = valid ? d : -1;
        if (lh == 0) sDst[r0] = mDst;

        // ---- A-fragments: 8 direct global loads ----
        half8 a[8];
        {
            const int adst = mDst < 0 ? mSrc : mDst;
            const _Float16* sp = &h16[(size_t)mSrc * H + lh * 8];
            const _Float16* dp = &h16[(size_t)adst * H + lh * 8];
            #pragma unroll
            for (int q = 0; q < 4; q++) a[q]     = *(const half8*)(sp + q * 32);
            #pragma unroll
            for (int q = 0; q < 4; q++) a[4 + q] = *(const half8*)(dp + q * 32);
        }

        // ---- emb fragments for macro-step 4 (slabs 8,9) ----
        half8 e8, e9;
        {
            const float* p = (lh == 0) ? &sRelE[mRel * 16]
                           : (lh == 1) ? &sRelE[mRel * 16 + 8]
                           : (lh == 2) ? &sRoleE[mRS * 8]
                                       : &sRoleE[mRD * 8];
            #pragma unroll
            for (int j = 0; j < 8; j++) e8[j] = (_Float16)p[j];
            if (lh < 2) {
                const float* q = (lh == 0) ? &sColE[mCS * 8] : &sColE[mCD * 8];
                #pragma unroll
                for (int j = 0; j < 8; j++) e9[j] = (_Float16)q[j];
            } else {
                #pragma unroll
                for (int j = 0; j < 8; j++) e9[j] = (_Float16)0.0f;
            }
        }

        // ---- B prologue: pair P0 (slabs 0,1) -> slot0; P1 -> pf[1] ----
        half8 pf[2][4];
        {
            half8 x0 = *(const half8*)(wp);
            half8 x1 = *(const half8*)(wp + 8);
            half8 x2 = *(const half8*)(wp + 4096);
            half8 x3 = *(const half8*)(wp + 4096 + 8);
            _Float16* w = &sB[tid * 16];
            *(half8*)(w)            = x0;
            *(half8*)(w + 8)        = x1;
            *(half8*)(w + 4096)     = x2;
            *(half8*)(w + 4096 + 8) = x3;
            pf[1][0] = *(const half8*)(wp + 2 * 4096);
            pf[1][1] = *(const half8*)(wp + 2 * 4096 + 8);
            pf[1][2] = *(const half8*)(wp + 3 * 4096);
            pf[1][3] = *(const half8*)(wp + 3 * 4096 + 8);
        }

        floatx4 acc[8];
        #pragma unroll
        for (int f = 0; f < 8; f++) acc[f] = (floatx4){0.f, 0.f, 0.f, 0.f};

        lgkm_barrier();   // slot0 + sDst visible

        // ---- MLP1: macro-steps 0..4 (pairs P0..P4) ----
        #pragma unroll
        for (int s = 0; s < 5; s++) {
            if (s + 2 <= 6) {
                const _Float16* bp = wp + (size_t)(2 * (s + 2)) * 4096;
                pf[s & 1][0] = *(const half8*)(bp);
                pf[s & 1][1] = *(const half8*)(bp + 8);
                pf[s & 1][2] = *(const half8*)(bp + 4096);
                pf[s & 1][3] = *(const half8*)(bp + 4096 + 8);
            }
            #pragma unroll
            for (int hh = 0; hh < 2; hh++) {
                half8 af = (s < 4) ? a[2 * s + hh] : (hh == 0 ? e8 : e9);
                #pragma unroll
                for (int f = 0; f < 8; f++) {
                    half8 bf = *(const half8*)&sB[(s & 1) * 8192 + hh * 4096 + (f * 64 + lane) * 8];
                    acc[f] = __builtin_amdgcn_mfma_f32_16x16x32_f16(af, bf, acc[f], 0, 0, 0);
                }
            }
            {   // write pair P(s+1) (loaded one step ago) to the other slot
                _Float16* w = &sB[((s + 1) & 1) * 8192 + tid * 16];
                *(half8*)(w)            = pf[(s + 1) & 1][0];
                *(half8*)(w + 8)        = pf[(s + 1) & 1][1];
                *(half8*)(w + 4096)     = pf[(s + 1) & 1][2];
                *(half8*)(w + 4096 + 8) = pf[(s + 1) & 1][3];
            }
            if (s < 4) lgkm_barrier();
        }

        // ---- transition: sY = silu(acc + eb1) (wave-local rows) ----
        #pragma unroll
        for (int f = 0; f < 8; f++) {
            const int col = f * 16 + lm;
            #pragma unroll
            for (int v = 0; v < 4; v++) {
                const int row = wv * 16 + lh * 4 + v;
                sY[row * 136 + col] = (_Float16)silu_f(acc[f][v] + bias1[f]);
            }
        }
        lgkm_barrier();   // P5 slab write + sY visible

        floatx4 acc2[8];
        #pragma unroll
        for (int f = 0; f < 8; f++) acc2[f] = (floatx4){0.f, 0.f, 0.f, 0.f};

        // ---- MLP2 macro-step 5: pair P5 (slabs 10,11) in slot1 ----
        #pragma unroll
        for (int hh = 0; hh < 2; hh++) {
            half8 af = *(const half8*)&sY[r0 * 136 + hh * 32 + lh * 8];
            #pragma unroll
            for (int f = 0; f < 8; f++) {
                half8 bf = *(const half8*)&sB[8192 + hh * 4096 + (f * 64 + lane) * 8];
                acc2[f] = __builtin_amdgcn_mfma_f32_16x16x32_f16(af, bf, acc2[f], 0, 0, 0);
            }
        }
        {   // write pair P6 (loaded at s=4 into pf[0]) -> slot0
            _Float16* w = &sB[tid * 16];
            *(half8*)(w)            = pf[0][0];
            *(half8*)(w + 8)        = pf[0][1];
            *(half8*)(w + 4096)     = pf[0][2];
            *(half8*)(w + 4096 + 8) = pf[0][3];
        }
        lgkm_barrier();

        // ---- MLP2 macro-step 6: pair P6 (slabs 12,13) in slot0 ----
        #pragma unroll
        for (int hh = 0; hh < 2; hh++) {
            half8 af = *(const half8*)&sY[r0 * 136 + 64 + hh * 32 + lh * 8];
            #pragma unroll
            for (int f = 0; f < 8; f++) {
                half8 bf = *(const half8*)&sB[hh * 4096 + (f * 64 + lane) * 8];
                acc2[f] = __builtin_amdgcn_mfma_f32_16x16x32_f16(af, bf, acc2[f], 0, 0, 0);
            }
        }
        lgkm_barrier();   // all sB/sY reads done -> M overlay is safe

        // ---- single-pass epilogue: M write, then run-length atomics ----
        #pragma unroll
        for (int f = 0; f < 8; f++) {
            const int col = f * 16 + lm;
            #pragma unroll
            for (int v = 0; v < 4; v++) {
                const int row = wv * 16 + lh * 4 + v;
                M[row * 132 + col] = silu_f(acc2[f][v] + bias2[f]);
            }
        }
        lgkm_barrier();
        {
            const int c  = tid & 127;
            const int g  = tid >> 7;          // 0,1 -> rows g*32..g*32+31
            const int rb = g * 32;
            float m[32]; int dd[32];
            #pragma unroll
            for (int i = 0; i < 32; i++) {
                m[i]  = M[(rb + i) * 132 + c];
                dd[i] = sDst[rb + i];
            }
            float acz = 0.0f; int cur = -1;
            #pragma unroll
            for (int i = 0; i < 32; i++) {
                if (dd[i] != cur) {
                    if (cur >= 0) unsafeAtomicAdd(&agg[cur * H + c], acz);
                    acz = 0.0f; cur = dd[i];
                }
                if (dd[i] >= 0) acz += m[i];
            }
            if (cur >= 0) unsafeAtomicAdd(&agg[cur * H + c], acz);
        }
    }
}

// ---------------------------------------------------------------------------
// Node kernel, fast path (R16, unchanged): 2-slab + 3-deep-reg pipeline,
// 13 slabs, raw lgkm barriers, one 64-row tile per block.
// ---------------------------------------------------------------------------
__global__ void __launch_bounds__(256, 4)
node_fast(const _Float16* __restrict__ h16, const float* __restrict__ agg,
          const float* __restrict__ h,
          const int* __restrict__ ncol, const int* __restrict__ nrole,
          const float* __restrict__ role_emb, const float* __restrict__ col_emb,
          const _Float16* __restrict__ nwf,   // [13][4096]
          const float* __restrict__ nb1, const float* __restrict__ nb2,
          const float* __restrict__ ln_g, const float* __restrict__ ln_b,
          float* __restrict__ out, int N)
{
    __shared__ __align__(16) _Float16 sB[2 * 4096];
    __shared__ __align__(16) _Float16 sY[64 * 136];
    __shared__ int sRole[64], sCol[64];
    __shared__ float sRoleE[48], sColE[24];

    const int tid  = threadIdx.x;
    const int lane = tid & 63;
    const int wv   = tid >> 6;
    const int lm   = lane & 15;
    const int lh   = lane >> 4;
    const int n0   = blockIdx.x * 64;
    const int r0   = wv * 16 + lm;
    const _Float16* wp = nwf + tid * 16;

    if (tid < 48) sRoleE[tid] = role_emb[tid];
    if (tid < 24) sColE[tid] = col_emb[tid];
    if (tid < 64) {
        int n = n0 + tid; if (n >= N) n = N - 1;
        sRole[tid] = nrole[n];
        sCol[tid]  = ncol[n];
    }

    half8 a[8];
    {
        int n = n0 + r0; if (n >= N) n = N - 1;
        const _Float16* hp = h16 + (size_t)n * H + lh * 8;
        #pragma unroll
        for (int s = 0; s < 4; s++) a[s] = *(const half8*)(hp + s * 32);
        const float* ap = agg + (size_t)n * H + lh * 8;
        #pragma unroll
        for (int s = 0; s < 4; s++) {
            float4 x = *(const float4*)(ap + s * 32);
            float4 y = *(const float4*)(ap + s * 32 + 4);
            a[4 + s] = cvt8(x, y);
        }
    }

    half8 pfa[3], pfb[3];
    {
        half8 s0a = *(const half8*)(wp);
        half8 s0b = *(const half8*)(wp + 8);
        *(half8*)&sB[tid * 16]     = s0a;
        *(half8*)&sB[tid * 16 + 8] = s0b;
        pfa[1] = *(const half8*)(wp + 1 * 4096);
        pfb[1] = *(const half8*)(wp + 1 * 4096 + 8);
        pfa[2] = *(const half8*)(wp + 2 * 4096);
        pfb[2] = *(const half8*)(wp + 2 * 4096 + 8);
    }

    floatx4 acc[8];
    #pragma unroll
    for (int f = 0; f < 8; f++) acc[f] = (floatx4){0.f, 0.f, 0.f, 0.f};

    lgkm_barrier();

    #pragma unroll
    for (int s = 0; s < 9; s++) {
        if (s + 3 <= 12) {
            pfa[s % 3] = *(const half8*)(wp + (s + 3) * 4096);
            pfb[s % 3] = *(const half8*)(wp + (s + 3) * 4096 + 8);
        }
        half8 af;
        if (s < 8) {
            af = a[s];
        } else {
            if (lh < 2) {
                const float* p = (lh == 0) ? &sRoleE[sRole[r0] * 8] : &sColE[sCol[r0] * 8];
                #pragma unroll
                for (int j = 0; j < 8; j++) af[j] = (_Float16)p[j];
            } else {
                #pragma unroll
                for (int j = 0; j < 8; j++) af[j] = (_Float16)0.0f;
            }
        }
        #pragma unroll
        for (int f = 0; f < 8; f++) {
            half8 bf = *(const half8*)&sB[(s & 1) * 4096 + (f * 64 + lane) * 8];
            acc[f] = __builtin_amdgcn_mfma_f32_16x16x32_f16(af, bf, acc[f], 0, 0, 0);
        }
        {
            _Float16* wdst = &sB[((s + 1) & 1) * 4096 + tid * 16];
            *(half8*)(wdst)     = pfa[(s + 1) % 3];
            *(half8*)(wdst + 8) = pfb[(s + 1) % 3];
        }
        lgkm_barrier();
    }

    #pragma unroll
    for (int f = 0; f < 8; f++) {
        const int col = f * 16 + lm;
        const float b1 = nb1[col];
        #pragma unroll
        for (int v = 0; v < 4; v++) {
            const int row = wv * 16 + lh * 4 + v;
            sY[row * 136 + col] = (_Float16)silu_f(acc[f][v] + b1);
        }
    }
    asm volatile("s_waitcnt lgkmcnt(0)" ::: "memory");
    __builtin_amdgcn_sched_barrier(0);

    floatx4 acc2[8];
    #pragma unroll
    for (int f = 0; f < 8; f++) acc2[f] = (floatx4){0.f, 0.f, 0.f, 0.f};

    #pragma unroll
    for (int s2 = 0; s2 < 4; s2++) {
        const int s = 9 + s2;
        if (s + 3 <= 12) {
            pfa[s % 3] = *(const half8*)(wp + (s + 3) * 4096);
            pfb[s % 3] = *(const half8*)(wp + (s + 3) * 4096 + 8);
        }
        half8 af = *(const half8*)&sY[r0 * 136 + s2 * 32 + lh * 8];
        #pragma unroll
        for (int f = 0; f < 8; f++) {
            half8 bf = *(const half8*)&sB[(s & 1) * 4096 + (f * 64 + lane) * 8];
            acc2[f] = __builtin_amdgcn_mfma_f32_16x16x32_f16(af, bf, acc2[f], 0, 0, 0);
        }
        if (s <= 11) {
            _Float16* wdst = &sB[((s + 1) & 1) * 4096 + tid * 16];
            *(half8*)(wdst)     = pfa[(s + 1) % 3];
            *(half8*)(wdst + 8) = pfb[(s + 1) % 3];
        }
        if (s2 < 3) lgkm_barrier();
    }

    float g[8], bb[8], b2[8];
    #pragma unroll
    for (int f = 0; f < 8; f++) {
        const int col = f * 16 + lm;
        g[f]  = ln_g[col];
        bb[f] = ln_b[col];
        b2[f] = nb2[col];
    }
    #pragma unroll
    for (int v = 0; v < 4; v++) {
        const int row = n0 + wv * 16 + lh * 4 + v;
        const int rc  = row < N ? row : N - 1;
        float x[8];
        float sum = 0.0f;
        #pragma unroll
        for (int f = 0; f < 8; f++) {
            const int col = f * 16 + lm;
            x[f] = h[(size_t)rc * H + col] + acc2[f][v] + b2[f];
            sum += x[f];
        }
        sum += __shfl_xor(sum, 1);
        sum += __shfl_xor(sum, 2);
        sum += __shfl_xor(sum, 4);
        sum += __shfl_xor(sum, 8);
        const float mu = sum * (1.0f / 128.0f);
        float vs = 0.0f;
        #pragma unroll
        for (int f = 0; f < 8; f++) { float dx = x[f] - mu; vs += dx * dx; }
        vs += __shfl_xor(vs, 1);
        vs += __shfl_xor(vs, 2);
        vs += __shfl_xor(vs, 4);
        vs += __shfl_xor(vs, 8);
        const float rstd = rsqrtf(vs * (1.0f / 128.0f) + LN_EPS);
        if (row < N) {
            #pragma unroll
            for (int f = 0; f < 8; f++) {
                const int col = f * 16 + lm;
                out[(size_t)row * H + col] = (x[f] - mu) * rstd * g[f] + bb[f];
            }
        }
    }
}

// ---------------------------------------------------------------------------
// Node kernel fallback (reads only d_in / d_ws).
// ---------------------------------------------------------------------------
__global__ void __launch_bounds__(256)
node_mfma(const float* __restrict__ h, const float* __restrict__ agg,
          const int* __restrict__ ncol, const int* __restrict__ nrole,
          const float* __restrict__ role_emb, const float* __restrict__ col_emb,
          const float* __restrict__ nW1, const float* __restrict__ nb1,
          const float* __restrict__ nW2, const float* __restrict__ nb2,
          const float* __restrict__ ln_g, const float* __restrict__ ln_b,
          float* __restrict__ out, int N)
{
    __shared__ _Float16 sA[64 * 40];
    __shared__ _Float16 sB[128 * 40];
    __shared__ _Float16 sY[64 * 136];
    __shared__ int sRole[64], sCol[64];
    __shared__ float sRoleE[48], sColE[24];

    const int tid  = threadIdx.x;
    const int lane = tid & 63;
    const int wv   = tid >> 6;
    const int lm   = lane & 15;
    const int lh   = lane >> 4;
    const int n0   = blockIdx.x * 64;

    if (tid < 48) sRoleE[tid] = role_emb[tid];
    if (tid < 24) sColE[tid] = col_emb[tid];
    if (tid < 64) {
        int n = n0 + tid; if (n >= N) n = N - 1;
        sRole[tid] = nrole[n];
        sCol[tid]  = ncol[n];
    }

    floatx4 acc[8];
    #pragma unroll
    for (int f = 0; f < 8; f++) acc[f] = (floatx4){0.f, 0.f, 0.f, 0.f};

    __syncthreads();

    for (int s = 0; s < 9; s++) {
        const int k0 = s * 32;
        {
            const int r  = tid >> 2;
            const int kq = (tid & 3) * 8;
            const int k  = k0 + kq;
            int n = n0 + r; if (n >= N) n = N - 1;
            float v[8];
            if (k < 128) {
                const float4* p = (const float4*)&h[n * H + k];
                float4 a = p[0], b = p[1];
                v[0]=a.x; v[1]=a.y; v[2]=a.z; v[3]=a.w;
                v[4]=b.x; v[5]=b.y; v[6]=b.z; v[7]=b.w;
            } else if (k < 256) {
                const float4* p = (const float4*)&agg[n * H + (k - 128)];
                float4 a = p[0], b = p[1];
                v[0]=a.x; v[1]=a.y; v[2]=a.z; v[3]=a.w;
                v[4]=b.x; v[5]=b.y; v[6]=b.z; v[7]=b.w;
            } else if (k < 264) {
                const float* p = &sRoleE[sRole[r] * 8 + (k - 256)];
                #pragma unroll
                for (int j = 0; j < 8; j++) v[j] = p[j];
            } else if (k < 272) {
                const float* p = &sColE[sCol[r] * 8 + (k - 264)];
                #pragma unroll
                for (int j = 0; j < 8; j++) v[j] = p[j];
            } else {
                #pragma unroll
                for (int j = 0; j < 8; j++) v[j] = 0.0f;
            }
            half8 o;
            #pragma unroll
            for (int j = 0; j < 8; j++) o[j] = (_Float16)v[j];
            *(half8*)&sA[r * 40 + kq] = o;
        }
        {
            const int n  = tid & 127;
            const int kh = (tid >> 7) * 16;
            #pragma unroll
            for (int i = 0; i < 16; i += 2) {
                const int ka = k0 + kh + i;
                const int kb = ka + 1;
                float wa = (ka < 272) ? nW1[ka * H + n] : 0.0f;
                float wb = (kb < 272) ? nW1[kb * H + n] : 0.0f;
                union { _Float16 f[2]; unsigned u; } pk;
                pk.f[0] = (_Float16)wa; pk.f[1] = (_Float16)wb;
                *(unsigned*)&sB[n * 40 + kh + i] = pk.u;
            }
        }
        __syncthreads();
        half8 af = *(const half8*)&sA[(wv * 16 + lm) * 40 + lh * 8];
        #pragma unroll
        for (int f = 0; f < 8; f++) {
            half8 bf = *(const half8*)&sB[(f * 16 + lm) * 40 + lh * 8];
            acc[f] = __builtin_amdgcn_mfma_f32_16x16x32_f16(af, bf, acc[f], 0, 0, 0);
        }
        __syncthreads();
    }

    #pragma unroll
    for (int f = 0; f < 8; f++) {
        const int col = f * 16 + lm;
        const float b1 = nb1[col];
        #pragma unroll
        for (int v = 0; v < 4; v++) {
            const int row = wv * 16 + lh * 4 + v;
            sY[row * 136 + col] = (_Float16)silu_f(acc[f][v] + b1);
        }
    }

    floatx4 acc2[8];
    #pragma unroll
    for (int f = 0; f < 8; f++) acc2[f] = (floatx4){0.f, 0.f, 0.f, 0.f};

    __syncthreads();

    for (int s2 = 0; s2 < 4; s2++) {
        {
            const int n  = tid & 127;
            const int kh = (tid >> 7) * 16;
            #pragma unroll
            for (int i = 0; i < 16; i += 2) {
                const int ka = s2 * 32 + kh + i;
                float wa = nW2[ka * H + n];
                float wb = nW2[(ka + 1) * H + n];
                union { _Float16 f[2]; unsigned u; } pk;
                pk.f[0] = (_Float16)wa; pk.f[1] = (_Float16)wb;
                *(unsigned*)&sB[n * 40 + kh + i] = pk.u;
            }
        }
        __syncthreads();
        half8 af = *(const half8*)&sY[(wv * 16 + lm) * 136 + s2 * 32 + lh * 8];
        #pragma unroll
        for (int f = 0; f < 8; f++) {
            half8 bf = *(const half8*)&sB[(f * 16 + lm) * 40 + lh * 8];
            acc2[f] = __builtin_amdgcn_mfma_f32_16x16x32_f16(af, bf, acc2[f], 0, 0, 0);
        }
        __syncthreads();
    }

    float g[8], bb[8], b2[8];
    #pragma unroll
    for (int f = 0; f < 8; f++) {
        const int col = f * 16 + lm;
        g[f]  = ln_g[col];
        bb[f] = ln_b[col];
        b2[f] = nb2[col];
    }
    #pragma unroll
    for (int v = 0; v < 4; v++) {
        const int row = n0 + wv * 16 + lh * 4 + v;
        const int rc  = row < N ? row : N - 1;
        float x[8];
        float sum = 0.0f;
        #pragma unroll
        for (int f = 0; f < 8; f++) {
            const int col = f * 16 + lm;
            x[f] = h[rc * H + col] + acc2[f][v] + b2[f];
            sum += x[f];
        }
        sum += __shfl_xor(sum, 1);
        sum += __shfl_xor(sum, 2);
        sum += __shfl_xor(sum, 4);
        sum += __shfl_xor(sum, 8);
        const float mu = sum * (1.0f / 128.0f);
        float vs = 0.0f;
        #pragma unroll
        for (int f = 0; f < 8; f++) { float dx = x[f] - mu; vs += dx * dx; }
        vs += __shfl_xor(vs, 1);
        vs += __shfl_xor(vs, 2);
        vs += __shfl_xor(vs, 4);
        vs += __shfl_xor(vs, 8);
        const float rstd = rsqrtf(vs * (1.0f / 128.0f) + LN_EPS);
        if (row < N) {
            #pragma unroll
            for (int f = 0; f < 8; f++) {
                const int col = f * 16 + lm;
                out[row * H + col] = (x[f] - mu) * rstd * g[f] + bb[f];
            }
        }
    }
}

extern "C" void kernel_launch(void* const* d_in, const int* in_sizes, int n_in,
                              void* d_out, int out_size, void* d_ws, size_t ws_size,
                              hipStream_t stream)
{
    const float* h        = (const float*)d_in[0];
    const int*   eidx     = (const int*)d_in[1];
    const int*   erel     = (const int*)d_in[2];
    const int*   ncol     = (const int*)d_in[3];
    const int*   nrole    = (const int*)d_in[4];
    const float* rel_emb  = (const float*)d_in[5];
    const float* role_emb = (const float*)d_in[6];
    const float* col_emb  = (const float*)d_in[7];
    const float* eW1      = (const float*)d_in[8];
    const float* eb1      = (const float*)d_in[9];
    const float* eW2      = (const float*)d_in[10];
    const float* eb2      = (const float*)d_in[11];
    const float* nW1      = (const float*)d_in[12];
    const float* nb1      = (const float*)d_in[13];
    const float* nW2      = (const float*)d_in[14];
    const float* nb2      = (const float*)d_in[15];
    const float* ln_g     = (const float*)d_in[16];
    const float* ln_b     = (const float*)d_in[17];

    const int N = in_sizes[0] / H;
    const int E = in_sizes[2];
    const int* esrc = eidx;
    const int* edst = eidx + E;
    const int bsz = (N + 7) / 8;

    float* agg = (float*)d_ws;

    // Sort scratch in d_out (dead before the node kernel writes out).
    int* perm   = (int*)d_out;
    int* cnt    = perm + E;
    int* base   = cnt + N;
    int* cursor = base + N;
    int* binfo  = cursor + N;

    size_t aggB   = (size_t)N * H * sizeof(float);
    size_t needWs = aggB + (size_t)N * H * 2 + (14 + 13) * 4096 * 2;
    const bool fast = (ws_size >= needWs);

    _Float16 *h16, *wef, *nwf;
    if (fast) {
        h16 = (_Float16*)((char*)d_ws + aggB);
        wef = h16 + (size_t)N * H;
        nwf = wef + 14 * 4096;
    } else {
        size_t io = (size_t)(E + 3 * N + 16);
        io = (io + 7) & ~(size_t)7;
        h16 = (_Float16*)(perm + io);
        wef = h16 + (size_t)N * H;
        nwf = wef + 14 * 4096;
    }

    hipMemsetAsync(agg, 0, aggB, stream);
    hipMemsetAsync(cnt, 0, (size_t)N * sizeof(int), stream);

    cvt_h16<<<(N * H / 8 + 255) / 256, 256, 0, stream>>>(h, h16, N * H / 8);
    cvt_weights<<<(27 * 4096 + 255) / 256, 256, 0, stream>>>(eW1, eW2, nW1, nW2, wef, nwf);

    hist2_kernel<<<512, 256, 0, stream>>>(edst, E, cnt);
    scan2_kernel<<<1, 1024, 0, stream>>>(cnt, base, cursor, N);
    binfo_kernel<<<1, 64, 0, stream>>>(base, N, bsz, E, binfo);
    scatter2_kernel<<<512, 256, 0, stream>>>(edst, E, cursor, perm);

    dim3 egrid(8, 96);
    edge_mfma<<<egrid, 256, 0, stream>>>(
        h16, perm, binfo, esrc, edst, erel, ncol, nrole,
        rel_emb, role_emb, col_emb, wef, eb1, eb2, agg);

    if (fast) {
        node_fast<<<(N + 63) / 64, 256, 0, stream>>>(
            h16, agg, h, ncol, nrole, role_emb, col_emb,
            nwf, nb1, nb2, ln_g, ln_b, (float*)d_out, N);
    } else {
        node_mfma<<<(N + 63) / 64, 256, 0, stream>>>(
            h, agg, ncol, nrole, role_emb, col_emb,
            nW1, nb1, nW2, nb2, ln_g, ln_b, (float*)d_out, N);
    }
}

// Round 18
// 394.274 us; speedup vs baseline: 1.3668x; 1.0252x over previous
//
#include <hip/hip_runtime.h>

#define H 128
#define LN_EPS 1e-5f

typedef _Float16 half8 __attribute__((ext_vector_type(8)));
typedef float floatx4 __attribute__((ext_vector_type(4)));

// fast silu: v_rcp_f32 instead of the precise-div sequence (~12 ops -> 2)
__device__ __forceinline__ float silu_f(float x) {
    return x * __builtin_amdgcn_rcpf(1.0f + __expf(-x));
}

// LDS-only barrier: waits ds-ops, leaves global loads in flight (no vmcnt drain).
__device__ __forceinline__ void lgkm_barrier() {
    asm volatile("s_waitcnt lgkmcnt(0)" ::: "memory");
    __builtin_amdgcn_s_barrier();
    __builtin_amdgcn_sched_barrier(0);
}

__device__ __forceinline__ half8 cvt8(float4 a, float4 b) {
    half8 o;
    o[0] = (_Float16)a.x; o[1] = (_Float16)a.y; o[2] = (_Float16)a.z; o[3] = (_Float16)a.w;
    o[4] = (_Float16)b.x; o[5] = (_Float16)b.y; o[6] = (_Float16)b.z; o[7] = (_Float16)b.w;
    return o;
}

// ---------------------------------------------------------------------------
// fp32 -> fp16 h table
// ---------------------------------------------------------------------------
__global__ void cvt_h16(const float* __restrict__ src, _Float16* __restrict__ dst,
                        int total8)
{
    int i = blockIdx.x * blockDim.x + threadIdx.x;
    if (i >= total8) return;
    const float4* p = (const float4*)(src + i * 8);
    *(half8*)(dst + i * 8) = cvt8(p[0], p[1]);
}

// All four weight matrices -> fragment-order fp16 slabs.
// wef: 14 slabs (eW1 10 + eW2 4); nwf: 13 slabs (nW1 9 + nW2 4).
// WF[slab][f][lane][j] = W[k = s*32+(lane>>4)*8+j][col = f*16+(lane&15)]
__global__ void cvt_weights(const float* __restrict__ eW1, const float* __restrict__ eW2,
                            const float* __restrict__ nW1, const float* __restrict__ nW2,
                            _Float16* __restrict__ wef, _Float16* __restrict__ nwf)
{
    int i = blockIdx.x * blockDim.x + threadIdx.x;
    if (i >= 27 * 4096) return;
    int j    = i & 7;
    int lane = (i >> 3) & 63;
    int f    = (i >> 9) & 7;
    int slab = i >> 12;
    int col  = f * 16 + (lane & 15);
    int kin  = (lane >> 4) * 8 + j;
    const float* W; int K, s; _Float16* dst; int di;
    if (slab < 10)      { W = eW1; K = 304; s = slab;      dst = wef; di = i; }
    else if (slab < 14) { W = eW2; K = 128; s = slab - 10; dst = wef; di = i; }
    else if (slab < 23) { W = nW1; K = 272; s = slab - 14; dst = nwf; di = i - 14 * 4096; }
    else                { W = nW2; K = 128; s = slab - 23; dst = nwf; di = i - 14 * 4096; }
    int k = s * 32 + kin;
    dst[di] = (k < K) ? (_Float16)W[k * H + col] : (_Float16)0.0f;
}

// ---------------------------------------------------------------------------
// Full counting sort by dst (N bins).
// ---------------------------------------------------------------------------
__global__ void hist2_kernel(const int* __restrict__ edst, int E,
                             int* __restrict__ cnt)
{
    for (int e = blockIdx.x * blockDim.x + threadIdx.x; e < E;
         e += gridDim.x * blockDim.x)
        atomicAdd(&cnt[edst[e]], 1);
}

__global__ void __launch_bounds__(1024)
scan2_kernel(const int* __restrict__ cnt, int* __restrict__ base,
             int* __restrict__ cursor, int N)
{
    __shared__ int wsum[16];
    __shared__ int woff[16];
    const int tid  = threadIdx.x;
    const int lane = tid & 63;
    const int w    = tid >> 6;
    const int chunk = (N + 1023) >> 10;
    const int lo = min(tid * chunk, N);
    const int hi = min(lo + chunk, N);
    int s = 0;
    for (int i = lo; i < hi; i++) s += cnt[i];
    int v = s;
    #pragma unroll
    for (int d = 1; d < 64; d <<= 1) {
        int u = __shfl_up(v, d);
        if (lane >= d) v += u;
    }
    if (lane == 63) wsum[w] = v;
    __syncthreads();
    if (tid == 0) {
        int r = 0;
        #pragma unroll
        for (int i = 0; i < 16; i++) { int c = wsum[i]; woff[i] = r; r += c; }
    }
    __syncthreads();
    int run = woff[w] + (v - s);
    for (int i = lo; i < hi; i++) {
        base[i] = run; cursor[i] = run;
        run += cnt[i];
    }
}

__global__ void binfo_kernel(const int* __restrict__ base, int N, int bsz, int E,
                             int* __restrict__ binfo)
{
    int b = threadIdx.x;
    if (b < 8) {
        int lo = min(b * bsz, N);
        int hi = min((b + 1) * bsz, N);
        int blo = (lo >= N) ? E : base[lo];
        int bhi = (hi >= N) ? E : base[hi];
        binfo[8 + b] = blo;
        binfo[b]     = bhi - blo;
    }
}

__global__ void scatter2_kernel(const int* __restrict__ edst, int E,
                                int* __restrict__ cursor, int* __restrict__ perm)
{
    for (int e = blockIdx.x * blockDim.x + threadIdx.x; e < E;
         e += gridDim.x * blockDim.x) {
        int p = atomicAdd(&cursor[edst[e]], 1);
        perm[p] = e;
    }
}

// ---------------------------------------------------------------------------
// Edge kernel: 64-edge tiles, dst-sorted.  K=64 macro-steps (7 steps: 5 MLP1
// + 2 MLP2) over paired slabs; 2x16KB LDS slots, 2-set register prefetch.
// Per-thread meta in regs; fp16 emb tables in LDS (built once per block) so
// emb fragments are single ds_read_b128s; fast-rcp silu; single-pass fp32-M
// epilogue with run-length atomics.
// ---------------------------------------------------------------------------
__global__ void __launch_bounds__(256, 3)
edge_mfma(const _Float16* __restrict__ h16,
          const int* __restrict__ perm, const int* __restrict__ binfo,
          const int* __restrict__ esrc, const int* __restrict__ edst,
          const int* __restrict__ erel, const int* __restrict__ ncol,
          const int* __restrict__ nrole,
          const float* __restrict__ rel_emb, const float* __restrict__ role_emb,
          const float* __restrict__ col_emb,
          const _Float16* __restrict__ wef,   // [14][4096] fragment-order
          const float* __restrict__ eb1, const float* __restrict__ eb2,
          float* __restrict__ agg)
{
    // uR: sB 2 slots x 8192 halfs (32768 B) | sY [64][136] fp16 (17408 B)
    //     M fp32 [64][132] (33792 B) overlays the front when sB/sY are dead.
    __shared__ __align__(16) unsigned char uR[50176];
    __shared__ int sDst[64];
    __shared__ __align__(16) _Float16 sRelE[128];
    __shared__ __align__(16) _Float16 sRoleE[48];
    __shared__ __align__(16) _Float16 sColE[24];

    _Float16* sB = (_Float16*)uR;               // 2 x 8192 halfs
    _Float16* sY = (_Float16*)(uR + 32768);     // [64][136]
    float*    M  = (float*)uR;                  // [64][132]

    const int tid  = threadIdx.x;
    const int lane = tid & 63;
    const int wv   = tid >> 6;
    const int lm   = lane & 15;
    const int lh   = lane >> 4;

    if (tid < 128) sRelE[tid] = (_Float16)rel_emb[tid];
    if (tid < 48)  sRoleE[tid] = (_Float16)role_emb[tid];
    if (tid < 24)  sColE[tid] = (_Float16)col_emb[tid];

    const int bucket = blockIdx.x;
    const int bcount = binfo[bucket];
    const int bbase  = binfo[8 + bucket];

    const int r0 = wv * 16 + lm;               // this thread's A row
    const _Float16* wp = wef + tid * 16;

    float bias1[8], bias2[8];
    #pragma unroll
    for (int f = 0; f < 8; f++) { bias1[f] = eb1[f * 16 + lm]; bias2[f] = eb2[f * 16 + lm]; }

    for (int t = blockIdx.y; t * 64 < bcount; t += gridDim.y)
    {
        lgkm_barrier();   // prev tile fully consumed (M reads, sDst reads)

        // ---- per-thread meta (redundant x4 per row; L1 broadcast) ----
        const int idx   = t * 64 + r0;
        const int valid = idx < bcount;
        const int e     = perm[bbase + (valid ? idx : 0)];
        const int mSrc  = esrc[e];
        const int d     = edst[e];
        const int mRel  = erel[e];
        const int mRS = nrole[mSrc], mRD = nrole[d];
        const int mCS = ncol[mSrc],  mCD = ncol[d];
        const int mDst = valid ? d : -1;
        if (lh == 0) sDst[r0] = mDst;

        // ---- A-fragments: 8 direct global loads ----
        half8 a[8];
        {
            const int adst = mDst < 0 ? mSrc : mDst;
            const _Float16* sp = &h16[(size_t)mSrc * H + lh * 8];
            const _Float16* dp = &h16[(size_t)adst * H + lh * 8];
            #pragma unroll
            for (int q = 0; q < 4; q++) a[q]     = *(const half8*)(sp + q * 32);
            #pragma unroll
            for (int q = 0; q < 4; q++) a[4 + q] = *(const half8*)(dp + q * 32);
        }

        // ---- emb fragments (macro-step 4, slabs 8,9): one b128 LDS read ----
        half8 e8, e9;
        {
            const _Float16* pe8 = (lh == 0) ? &sRelE[mRel * 16]
                                : (lh == 1) ? &sRelE[mRel * 16 + 8]
                                : (lh == 2) ? &sRoleE[mRS * 8]
                                            : &sRoleE[mRD * 8];
            e8 = *(const half8*)pe8;
            if (lh < 2) {
                const _Float16* pe9 = (lh == 0) ? &sColE[mCS * 8] : &sColE[mCD * 8];
                e9 = *(const half8*)pe9;
            } else {
                #pragma unroll
                for (int j = 0; j < 8; j++) e9[j] = (_Float16)0.0f;
            }
        }

        // ---- B prologue: pair P0 (slabs 0,1) -> slot0; P1 -> pf[1] ----
        half8 pf[2][4];
        {
            half8 x0 = *(const half8*)(wp);
            half8 x1 = *(const half8*)(wp + 8);
            half8 x2 = *(const half8*)(wp + 4096);
            half8 x3 = *(const half8*)(wp + 4096 + 8);
            _Float16* w = &sB[tid * 16];
            *(half8*)(w)            = x0;
            *(half8*)(w + 8)        = x1;
            *(half8*)(w + 4096)     = x2;
            *(half8*)(w + 4096 + 8) = x3;
            pf[1][0] = *(const half8*)(wp + 2 * 4096);
            pf[1][1] = *(const half8*)(wp + 2 * 4096 + 8);
            pf[1][2] = *(const half8*)(wp + 3 * 4096);
            pf[1][3] = *(const half8*)(wp + 3 * 4096 + 8);
        }

        floatx4 acc[8];
        #pragma unroll
        for (int f = 0; f < 8; f++) acc[f] = (floatx4){0.f, 0.f, 0.f, 0.f};

        lgkm_barrier();   // slot0 + sDst visible

        // ---- MLP1: macro-steps 0..4 (pairs P0..P4) ----
        #pragma unroll
        for (int s = 0; s < 5; s++) {
            if (s + 2 <= 6) {
                const _Float16* bp = wp + (size_t)(2 * (s + 2)) * 4096;
                pf[s & 1][0] = *(const half8*)(bp);
                pf[s & 1][1] = *(const half8*)(bp + 8);
                pf[s & 1][2] = *(const half8*)(bp + 4096);
                pf[s & 1][3] = *(const half8*)(bp + 4096 + 8);
            }
            #pragma unroll
            for (int hh = 0; hh < 2; hh++) {
                half8 af = (s < 4) ? a[2 * s + hh] : (hh == 0 ? e8 : e9);
                #pragma unroll
                for (int f = 0; f < 8; f++) {
                    half8 bf = *(const half8*)&sB[(s & 1) * 8192 + hh * 4096 + (f * 64 + lane) * 8];
                    acc[f] = __builtin_amdgcn_mfma_f32_16x16x32_f16(af, bf, acc[f], 0, 0, 0);
                }
            }
            {   // write pair P(s+1) (loaded one step ago) to the other slot
                _Float16* w = &sB[((s + 1) & 1) * 8192 + tid * 16];
                *(half8*)(w)            = pf[(s + 1) & 1][0];
                *(half8*)(w + 8)        = pf[(s + 1) & 1][1];
                *(half8*)(w + 4096)     = pf[(s + 1) & 1][2];
                *(half8*)(w + 4096 + 8) = pf[(s + 1) & 1][3];
            }
            if (s < 4) lgkm_barrier();
        }

        // ---- transition: sY = silu(acc + eb1) (wave-local rows) ----
        #pragma unroll
        for (int f = 0; f < 8; f++) {
            const int col = f * 16 + lm;
            #pragma unroll
            for (int v = 0; v < 4; v++) {
                const int row = wv * 16 + lh * 4 + v;
                sY[row * 136 + col] = (_Float16)silu_f(acc[f][v] + bias1[f]);
            }
        }
        lgkm_barrier();   // P5 slab write + sY visible

        floatx4 acc2[8];
        #pragma unroll
        for (int f = 0; f < 8; f++) acc2[f] = (floatx4){0.f, 0.f, 0.f, 0.f};

        // ---- MLP2 macro-step 5: pair P5 (slabs 10,11) in slot1 ----
        #pragma unroll
        for (int hh = 0; hh < 2; hh++) {
            half8 af = *(const half8*)&sY[r0 * 136 + hh * 32 + lh * 8];
            #pragma unroll
            for (int f = 0; f < 8; f++) {
                half8 bf = *(const half8*)&sB[8192 + hh * 4096 + (f * 64 + lane) * 8];
                acc2[f] = __builtin_amdgcn_mfma_f32_16x16x32_f16(af, bf, acc2[f], 0, 0, 0);
            }
        }
        {   // write pair P6 (loaded at s=4 into pf[0]) -> slot0
            _Float16* w = &sB[tid * 16];
            *(half8*)(w)            = pf[0][0];
            *(half8*)(w + 8)        = pf[0][1];
            *(half8*)(w + 4096)     = pf[0][2];
            *(half8*)(w + 4096 + 8) = pf[0][3];
        }
        lgkm_barrier();

        // ---- MLP2 macro-step 6: pair P6 (slabs 12,13) in slot0 ----
        #pragma unroll
        for (int hh = 0; hh < 2; hh++) {
            half8 af = *(const half8*)&sY[r0 * 136 + 64 + hh * 32 + lh * 8];
            #pragma unroll
            for (int f = 0; f < 8; f++) {
                half8 bf = *(const half8*)&sB[hh * 4096 + (f * 64 + lane) * 8];
                acc2[f] = __builtin_amdgcn_mfma_f32_16x16x32_f16(af, bf, acc2[f], 0, 0, 0);
            }
        }
        lgkm_barrier();   // all sB/sY reads done -> M overlay is safe

        // ---- single-pass epilogue: M write, then run-length atomics ----
        #pragma unroll
        for (int f = 0; f < 8; f++) {
            const int col = f * 16 + lm;
            #pragma unroll
            for (int v = 0; v < 4; v++) {
                const int row = wv * 16 + lh * 4 + v;
                M[row * 132 + col] = silu_f(acc2[f][v] + bias2[f]);
            }
        }
        lgkm_barrier();
        {
            const int c  = tid & 127;
            const int g  = tid >> 7;          // 0,1 -> rows g*32..g*32+31
            const int rb = g * 32;
            float m[32]; int dd[32];
            #pragma unroll
            for (int i = 0; i < 32; i++) {
                m[i]  = M[(rb + i) * 132 + c];
                dd[i] = sDst[rb + i];
            }
            float acz = 0.0f; int cur = -1;
            #pragma unroll
            for (int i = 0; i < 32; i++) {
                if (dd[i] != cur) {
                    if (cur >= 0) unsafeAtomicAdd(&agg[cur * H + c], acz);
                    acz = 0.0f; cur = dd[i];
                }
                if (dd[i] >= 0) acz += m[i];
            }
            if (cur >= 0) unsafeAtomicAdd(&agg[cur * H + c], acz);
        }
    }
}

// ---------------------------------------------------------------------------
// Node kernel, fast path: 2-slab + 3-deep-reg pipeline, 13 slabs, raw lgkm
// barriers, fp16 emb tables, fast silu.
// ---------------------------------------------------------------------------
__global__ void __launch_bounds__(256, 4)
node_fast(const _Float16* __restrict__ h16, const float* __restrict__ agg,
          const float* __restrict__ h,
          const int* __restrict__ ncol, const int* __restrict__ nrole,
          const float* __restrict__ role_emb, const float* __restrict__ col_emb,
          const _Float16* __restrict__ nwf,   // [13][4096]
          const float* __restrict__ nb1, const float* __restrict__ nb2,
          const float* __restrict__ ln_g, const float* __restrict__ ln_b,
          float* __restrict__ out, int N)
{
    __shared__ __align__(16) _Float16 sB[2 * 4096];
    __shared__ __align__(16) _Float16 sY[64 * 136];
    __shared__ int sRole[64], sCol[64];
    __shared__ __align__(16) _Float16 sRoleE[48];
    __shared__ __align__(16) _Float16 sColE[24];

    const int tid  = threadIdx.x;
    const int lane = tid & 63;
    const int wv   = tid >> 6;
    const int lm   = lane & 15;
    const int lh   = lane >> 4;
    const int n0   = blockIdx.x * 64;
    const int r0   = wv * 16 + lm;
    const _Float16* wp = nwf + tid * 16;

    if (tid < 48) sRoleE[tid] = (_Float16)role_emb[tid];
    if (tid < 24) sColE[tid] = (_Float16)col_emb[tid];
    if (tid < 64) {
        int n = n0 + tid; if (n >= N) n = N - 1;
        sRole[tid] = nrole[n];
        sCol[tid]  = ncol[n];
    }

    half8 a[8];
    {
        int n = n0 + r0; if (n >= N) n = N - 1;
        const _Float16* hp = h16 + (size_t)n * H + lh * 8;
        #pragma unroll
        for (int s = 0; s < 4; s++) a[s] = *(const half8*)(hp + s * 32);
        const float* ap = agg + (size_t)n * H + lh * 8;
        #pragma unroll
        for (int s = 0; s < 4; s++) {
            float4 x = *(const float4*)(ap + s * 32);
            float4 y = *(const float4*)(ap + s * 32 + 4);
            a[4 + s] = cvt8(x, y);
        }
    }

    half8 pfa[3], pfb[3];
    {
        half8 s0a = *(const half8*)(wp);
        half8 s0b = *(const half8*)(wp + 8);
        *(half8*)&sB[tid * 16]     = s0a;
        *(half8*)&sB[tid * 16 + 8] = s0b;
        pfa[1] = *(const half8*)(wp + 1 * 4096);
        pfb[1] = *(const half8*)(wp + 1 * 4096 + 8);
        pfa[2] = *(const half8*)(wp + 2 * 4096);
        pfb[2] = *(const half8*)(wp + 2 * 4096 + 8);
    }

    floatx4 acc[8];
    #pragma unroll
    for (int f = 0; f < 8; f++) acc[f] = (floatx4){0.f, 0.f, 0.f, 0.f};

    lgkm_barrier();

    #pragma unroll
    for (int s = 0; s < 9; s++) {
        if (s + 3 <= 12) {
            pfa[s % 3] = *(const half8*)(wp + (s + 3) * 4096);
            pfb[s % 3] = *(const half8*)(wp + (s + 3) * 4096 + 8);
        }
        half8 af;
        if (s < 8) {
            af = a[s];
        } else {
            if (lh < 2) {
                const _Float16* p = (lh == 0) ? &sRoleE[sRole[r0] * 8] : &sColE[sCol[r0] * 8];
                af = *(const half8*)p;
            } else {
                #pragma unroll
                for (int j = 0; j < 8; j++) af[j] = (_Float16)0.0f;
            }
        }
        #pragma unroll
        for (int f = 0; f < 8; f++) {
            half8 bf = *(const half8*)&sB[(s & 1) * 4096 + (f * 64 + lane) * 8];
            acc[f] = __builtin_amdgcn_mfma_f32_16x16x32_f16(af, bf, acc[f], 0, 0, 0);
        }
        {
            _Float16* wdst = &sB[((s + 1) & 1) * 4096 + tid * 16];
            *(half8*)(wdst)     = pfa[(s + 1) % 3];
            *(half8*)(wdst + 8) = pfb[(s + 1) % 3];
        }
        lgkm_barrier();
    }

    #pragma unroll
    for (int f = 0; f < 8; f++) {
        const int col = f * 16 + lm;
        const float b1 = nb1[col];
        #pragma unroll
        for (int v = 0; v < 4; v++) {
            const int row = wv * 16 + lh * 4 + v;
            sY[row * 136 + col] = (_Float16)silu_f(acc[f][v] + b1);
        }
    }
    asm volatile("s_waitcnt lgkmcnt(0)" ::: "memory");
    __builtin_amdgcn_sched_barrier(0);

    floatx4 acc2[8];
    #pragma unroll
    for (int f = 0; f < 8; f++) acc2[f] = (floatx4){0.f, 0.f, 0.f, 0.f};

    #pragma unroll
    for (int s2 = 0; s2 < 4; s2++) {
        const int s = 9 + s2;
        if (s + 3 <= 12) {
            pfa[s % 3] = *(const half8*)(wp + (s + 3) * 4096);
            pfb[s % 3] = *(const half8*)(wp + (s + 3) * 4096 + 8);
        }
        half8 af = *(const half8*)&sY[r0 * 136 + s2 * 32 + lh * 8];
        #pragma unroll
        for (int f = 0; f < 8; f++) {
            half8 bf = *(const half8*)&sB[(s & 1) * 4096 + (f * 64 + lane) * 8];
            acc2[f] = __builtin_amdgcn_mfma_f32_16x16x32_f16(af, bf, acc2[f], 0, 0, 0);
        }
        if (s <= 11) {
            _Float16* wdst = &sB[((s + 1) & 1) * 4096 + tid * 16];
            *(half8*)(wdst)     = pfa[(s + 1) % 3];
            *(half8*)(wdst + 8) = pfb[(s + 1) % 3];
        }
        if (s2 < 3) lgkm_barrier();
    }

    float g[8], bb[8], b2[8];
    #pragma unroll
    for (int f = 0; f < 8; f++) {
        const int col = f * 16 + lm;
        g[f]  = ln_g[col];
        bb[f] = ln_b[col];
        b2[f] = nb2[col];
    }
    #pragma unroll
    for (int v = 0; v < 4; v++) {
        const int row = n0 + wv * 16 + lh * 4 + v;
        const int rc  = row < N ? row : N - 1;
        float x[8];
        float sum = 0.0f;
        #pragma unroll
        for (int f = 0; f < 8; f++) {
            const int col = f * 16 + lm;
            x[f] = h[(size_t)rc * H + col] + acc2[f][v] + b2[f];
            sum += x[f];
        }
        sum += __shfl_xor(sum, 1);
        sum += __shfl_xor(sum, 2);
        sum += __shfl_xor(sum, 4);
        sum += __shfl_xor(sum, 8);
        const float mu = sum * (1.0f / 128.0f);
        float vs = 0.0f;
        #pragma unroll
        for (int f = 0; f < 8; f++) { float dx = x[f] - mu; vs += dx * dx; }
        vs += __shfl_xor(vs, 1);
        vs += __shfl_xor(vs, 2);
        vs += __shfl_xor(vs, 4);
        vs += __shfl_xor(vs, 8);
        const float rstd = rsqrtf(vs * (1.0f / 128.0f) + LN_EPS);
        if (row < N) {
            #pragma unroll
            for (int f = 0; f < 8; f++) {
                const int col = f * 16 + lm;
                out[(size_t)row * H + col] = (x[f] - mu) * rstd * g[f] + bb[f];
            }
        }
    }
}

// ---------------------------------------------------------------------------
// Node kernel fallback (reads only d_in / d_ws).
// ---------------------------------------------------------------------------
__global__ void __launch_bounds__(256)
node_mfma(const float* __restrict__ h, const float* __restrict__ agg,
          const int* __restrict__ ncol, const int* __restrict__ nrole,
          const float* __restrict__ role_emb, const float* __restrict__ col_emb,
          const float* __restrict__ nW1, const float* __restrict__ nb1,
          const float* __restrict__ nW2, const float* __restrict__ nb2,
          const float* __restrict__ ln_g, const float* __restrict__ ln_b,
          float* __restrict__ out, int N)
{
    __shared__ _Float16 sA[64 * 40];
    __shared__ _Float16 sB[128 * 40];
    __shared__ _Float16 sY[64 * 136];
    __shared__ int sRole[64], sCol[64];
    __shared__ float sRoleE[48], sColE[24];

    const int tid  = threadIdx.x;
    const int lane = tid & 63;
    const int wv   = tid >> 6;
    const int lm   = lane & 15;
    const int lh   = lane >> 4;
    const int n0   = blockIdx.x * 64;

    if (tid < 48) sRoleE[tid] = role_emb[tid];
    if (tid < 24) sColE[tid] = col_emb[tid];
    if (tid < 64) {
        int n = n0 + tid; if (n >= N) n = N - 1;
        sRole[tid] = nrole[n];
        sCol[tid]  = ncol[n];
    }

    floatx4 acc[8];
    #pragma unroll
    for (int f = 0; f < 8; f++) acc[f] = (floatx4){0.f, 0.f, 0.f, 0.f};

    __syncthreads();

    for (int s = 0; s < 9; s++) {
        const int k0 = s * 32;
        {
            const int r  = tid >> 2;
            const int kq = (tid & 3) * 8;
            const int k  = k0 + kq;
            int n = n0 + r; if (n >= N) n = N - 1;
            float v[8];
            if (k < 128) {
                const float4* p = (const float4*)&h[n * H + k];
                float4 a = p[0], b = p[1];
                v[0]=a.x; v[1]=a.y; v[2]=a.z; v[3]=a.w;
                v[4]=b.x; v[5]=b.y; v[6]=b.z; v[7]=b.w;
            } else if (k < 256) {
                const float4* p = (const float4*)&agg[n * H + (k - 128)];
                float4 a = p[0], b = p[1];
                v[0]=a.x; v[1]=a.y; v[2]=a.z; v[3]=a.w;
                v[4]=b.x; v[5]=b.y; v[6]=b.z; v[7]=b.w;
            } else if (k < 264) {
                const float* p = &sRoleE[sRole[r] * 8 + (k - 256)];
                #pragma unroll
                for (int j = 0; j < 8; j++) v[j] = p[j];
            } else if (k < 272) {
                const float* p = &sColE[sCol[r] * 8 + (k - 264)];
                #pragma unroll
                for (int j = 0; j < 8; j++) v[j] = p[j];
            } else {
                #pragma unroll
                for (int j = 0; j < 8; j++) v[j] = 0.0f;
            }
            half8 o;
            #pragma unroll
            for (int j = 0; j < 8; j++) o[j] = (_Float16)v[j];
            *(half8*)&sA[r * 40 + kq] = o;
        }
        {
            const int n  = tid & 127;
            const int kh = (tid >> 7) * 16;
            #pragma unroll
            for (int i = 0; i < 16; i += 2) {
                const int ka = k0 + kh + i;
                const int kb = ka + 1;
                float wa = (ka < 272) ? nW1[ka * H + n] : 0.0f;
                float wb = (kb < 272) ? nW1[kb * H + n] : 0.0f;
                union { _Float16 f[2]; unsigned u; } pk;
                pk.f[0] = (_Float16)wa; pk.f[1] = (_Float16)wb;
                *(unsigned*)&sB[n * 40 + kh + i] = pk.u;
            }
        }
        __syncthreads();
        half8 af = *(const half8*)&sA[(wv * 16 + lm) * 40 + lh * 8];
        #pragma unroll
        for (int f = 0; f < 8; f++) {
            half8 bf = *(const half8*)&sB[(f * 16 + lm) * 40 + lh * 8];
            acc[f] = __builtin_amdgcn_mfma_f32_16x16x32_f16(af, bf, acc[f], 0, 0, 0);
        }
        __syncthreads();
    }

    #pragma unroll
    for (int f = 0; f < 8; f++) {
        const int col = f * 16 + lm;
        const float b1 = nb1[col];
        #pragma unroll
        for (int v = 0; v < 4; v++) {
            const int row = wv * 16 + lh * 4 + v;
            sY[row * 136 + col] = (_Float16)silu_f(acc[f][v] + b1);
        }
    }

    floatx4 acc2[8];
    #pragma unroll
    for (int f = 0; f < 8; f++) acc2[f] = (floatx4){0.f, 0.f, 0.f, 0.f};

    __syncthreads();

    for (int s2 = 0; s2 < 4; s2++) {
        {
            const int n  = tid & 127;
            const int kh = (tid >> 7) * 16;
            #pragma unroll
            for (int i = 0; i < 16; i += 2) {
                const int ka = s2 * 32 + kh + i;
                float wa = nW2[ka * H + n];
                float wb = nW2[(ka + 1) * H + n];
                union { _Float16 f[2]; unsigned u; } pk;
                pk.f[0] = (_Float16)wa; pk.f[1] = (_Float16)wb;
                *(unsigned*)&sB[n * 40 + kh + i] = pk.u;
            }
        }
        __syncthreads();
        half8 af = *(const half8*)&sY[(wv * 16 + lm) * 136 + s2 * 32 + lh * 8];
        #pragma unroll
        for (int f = 0; f < 8; f++) {
            half8 bf = *(const half8*)&sB[(f * 16 + lm) * 40 + lh * 8];
            acc2[f] = __builtin_amdgcn_mfma_f32_16x16x32_f16(af, bf, acc2[f], 0, 0, 0);
        }
        __syncthreads();
    }

    float g[8], bb[8], b2[8];
    #pragma unroll
    for (int f = 0; f < 8; f++) {
        const int col = f * 16 + lm;
        g[f]  = ln_g[col];
        bb[f] = ln_b[col];
        b2[f] = nb2[col];
    }
    #pragma unroll
    for (int v = 0; v < 4; v++) {
        const int row = n0 + wv * 16 + lh * 4 + v;
        const int rc  = row < N ? row : N - 1;
        float x[8];
        float sum = 0.0f;
        #pragma unroll
        for (int f = 0; f < 8; f++) {
            const int col = f * 16 + lm;
            x[f] = h[rc * H + col] + acc2[f][v] + b2[f];
            sum += x[f];
        }
        sum += __shfl_xor(sum, 1);
        sum += __shfl_xor(sum, 2);
        sum += __shfl_xor(sum, 4);
        sum += __shfl_xor(sum, 8);
        const float mu = sum * (1.0f / 128.0f);
        float vs = 0.0f;
        #pragma unroll
        for (int f = 0; f < 8; f++) { float dx = x[f] - mu; vs += dx * dx; }
        vs += __shfl_xor(vs, 1);
        vs += __shfl_xor(vs, 2);
        vs += __shfl_xor(vs, 4);
        vs += __shfl_xor(vs, 8);
        const float rstd = rsqrtf(vs * (1.0f / 128.0f) + LN_EPS);
        if (row < N) {
            #pragma unroll
            for (int f = 0; f < 8; f++) {
                const int col = f * 16 + lm;
                out[row * H + col] = (x[f] - mu) * rstd * g[f] + bb[f];
            }
        }
    }
}

extern "C" void kernel_launch(void* const* d_in, const int* in_sizes, int n_in,
                              void* d_out, int out_size, void* d_ws, size_t ws_size,
                              hipStream_t stream)
{
    const float* h        = (const float*)d_in[0];
    const int*   eidx     = (const int*)d_in[1];
    const int*   erel     = (const int*)d_in[2];
    const int*   ncol     = (const int*)d_in[3];
    const int*   nrole    = (const int*)d_in[4];
    const float* rel_emb  = (const float*)d_in[5];
    const float* role_emb = (const float*)d_in[6];
    const float* col_emb  = (const float*)d_in[7];
    const float* eW1      = (const float*)d_in[8];
    const float* eb1      = (const float*)d_in[9];
    const float* eW2      = (const float*)d_in[10];
    const float* eb2      = (const float*)d_in[11];
    const float* nW1      = (const float*)d_in[12];
    const float* nb1      = (const float*)d_in[13];
    const float* nW2      = (const float*)d_in[14];
    const float* nb2      = (const float*)d_in[15];
    const float* ln_g     = (const float*)d_in[16];
    const float* ln_b     = (const float*)d_in[17];

    const int N = in_sizes[0] / H;
    const int E = in_sizes[2];
    const int* esrc = eidx;
    const int* edst = eidx + E;
    const int bsz = (N + 7) / 8;

    float* agg = (float*)d_ws;

    // Sort scratch in d_out (dead before the node kernel writes out).
    int* perm   = (int*)d_out;
    int* cnt    = perm + E;
    int* base   = cnt + N;
    int* cursor = base + N;
    int* binfo  = cursor + N;

    size_t aggB   = (size_t)N * H * sizeof(float);
    size_t needWs = aggB + (size_t)N * H * 2 + (14 + 13) * 4096 * 2;
    const bool fast = (ws_size >= needWs);

    _Float16 *h16, *wef, *nwf;
    if (fast) {
        h16 = (_Float16*)((char*)d_ws + aggB);
        wef = h16 + (size_t)N * H;
        nwf = wef + 14 * 4096;
    } else {
        size_t io = (size_t)(E + 3 * N + 16);
        io = (io + 7) & ~(size_t)7;
        h16 = (_Float16*)(perm + io);
        wef = h16 + (size_t)N * H;
        nwf = wef + 14 * 4096;
    }

    hipMemsetAsync(agg, 0, aggB, stream);
    hipMemsetAsync(cnt, 0, (size_t)N * sizeof(int), stream);

    cvt_h16<<<(N * H / 8 + 255) / 256, 256, 0, stream>>>(h, h16, N * H / 8);
    cvt_weights<<<(27 * 4096 + 255) / 256, 256, 0, stream>>>(eW1, eW2, nW1, nW2, wef, nwf);

    hist2_kernel<<<512, 256, 0, stream>>>(edst, E, cnt);
    scan2_kernel<<<1, 1024, 0, stream>>>(cnt, base, cursor, N);
    binfo_kernel<<<1, 64, 0, stream>>>(base, N, bsz, E, binfo);
    scatter2_kernel<<<512, 256, 0, stream>>>(edst, E, cursor, perm);

    dim3 egrid(8, 96);
    edge_mfma<<<egrid, 256, 0, stream>>>(
        h16, perm, binfo, esrc, edst, erel, ncol, nrole,
        rel_emb, role_emb, col_emb, wef, eb1, eb2, agg);

    if (fast) {
        node_fast<<<(N + 63) / 64, 256, 0, stream>>>(
            h16, agg, h, ncol, nrole, role_emb, col_emb,
            nwf, nb1, nb2, ln_g, ln_b, (float*)d_out, N);
    } else {
        node_mfma<<<(N + 63) / 64, 256, 0, stream>>>(
            h, agg, ncol, nrole, role_emb, col_emb,
            nW1, nb1, nW2, nb2, ln_g, ln_b, (float*)d_out, N);
    }
}

// Round 19
// 382.012 us; speedup vs baseline: 1.4107x; 1.0321x over previous
//
#include <hip/hip_runtime.h>

#define H 128
#define LN_EPS 1e-5f

typedef _Float16 half8 __attribute__((ext_vector_type(8)));
typedef float floatx4 __attribute__((ext_vector_type(4)));

// fast silu: v_rcp_f32 instead of the precise-div sequence (~12 ops -> 2)
__device__ __forceinline__ float silu_f(float x) {
    return x * __builtin_amdgcn_rcpf(1.0f + __expf(-x));
}

// LDS-only barrier: waits ds-ops, leaves global loads in flight (no vmcnt drain).
__device__ __forceinline__ void lgkm_barrier() {
    asm volatile("s_waitcnt lgkmcnt(0)" ::: "memory");
    __builtin_amdgcn_s_barrier();
    __builtin_amdgcn_sched_barrier(0);
}

__device__ __forceinline__ half8 cvt8(float4 a, float4 b) {
    half8 o;
    o[0] = (_Float16)a.x; o[1] = (_Float16)a.y; o[2] = (_Float16)a.z; o[3] = (_Float16)a.w;
    o[4] = (_Float16)b.x; o[5] = (_Float16)b.y; o[6] = (_Float16)b.z; o[7] = (_Float16)b.w;
    return o;
}

// ---------------------------------------------------------------------------
// Fused prep: zero agg (float4), zero cnt (int), fp32->fp16 h table (half8),
// weight tables (per-element).  One dispatch replaces 4.
// ---------------------------------------------------------------------------
__global__ void prep_kernel(const float* __restrict__ h, _Float16* __restrict__ h16,
                            int nh8,
                            const float* __restrict__ eW1, const float* __restrict__ eW2,
                            const float* __restrict__ nW1, const float* __restrict__ nW2,
                            _Float16* __restrict__ wef, _Float16* __restrict__ nwf,
                            float* __restrict__ agg, int nagg4,
                            int* __restrict__ cnt, int ncnt)
{
    const int i = blockIdx.x * blockDim.x + threadIdx.x;
    if (i < nagg4) {
        ((float4*)agg)[i] = make_float4(0.f, 0.f, 0.f, 0.f);
        return;
    }
    int j = i - nagg4;
    if (j < nh8) {
        const float4* p = (const float4*)(h + (size_t)j * 8);
        *(half8*)(h16 + (size_t)j * 8) = cvt8(p[0], p[1]);
        return;
    }
    j -= nh8;
    if (j < 27 * 4096) {
        int jj   = j & 7;
        int lane = (j >> 3) & 63;
        int f    = (j >> 9) & 7;
        int slab = j >> 12;
        int col  = f * 16 + (lane & 15);
        int kin  = (lane >> 4) * 8 + jj;
        const float* W; int K, s; _Float16* dst; int di;
        if (slab < 10)      { W = eW1; K = 304; s = slab;      dst = wef; di = j; }
        else if (slab < 14) { W = eW2; K = 128; s = slab - 10; dst = wef; di = j; }
        else if (slab < 23) { W = nW1; K = 272; s = slab - 14; dst = nwf; di = j - 14 * 4096; }
        else                { W = nW2; K = 128; s = slab - 23; dst = nwf; di = j - 14 * 4096; }
        int k = s * 32 + kin;
        dst[di] = (k < K) ? (_Float16)W[k * H + col] : (_Float16)0.0f;
        return;
    }
    j -= 27 * 4096;
    if (j < ncnt) cnt[j] = 0;
}

// ---------------------------------------------------------------------------
// Full counting sort by dst (N bins).
// ---------------------------------------------------------------------------
__global__ void hist2_kernel(const int* __restrict__ edst, int E,
                             int* __restrict__ cnt)
{
    for (int e = blockIdx.x * blockDim.x + threadIdx.x; e < E;
         e += gridDim.x * blockDim.x)
        atomicAdd(&cnt[edst[e]], 1);
}

// scan + binfo fused (single block; __syncthreads orders global writes).
__global__ void __launch_bounds__(1024)
scan2_kernel(const int* __restrict__ cnt, int* __restrict__ base,
             int* __restrict__ cursor, int N, int bsz, int E,
             int* __restrict__ binfo)
{
    __shared__ int wsum[16];
    __shared__ int woff[16];
    const int tid  = threadIdx.x;
    const int lane = tid & 63;
    const int w    = tid >> 6;
    const int chunk = (N + 1023) >> 10;
    const int lo = min(tid * chunk, N);
    const int hi = min(lo + chunk, N);
    int s = 0;
    for (int i = lo; i < hi; i++) s += cnt[i];
    int v = s;
    #pragma unroll
    for (int d = 1; d < 64; d <<= 1) {
        int u = __shfl_up(v, d);
        if (lane >= d) v += u;
    }
    if (lane == 63) wsum[w] = v;
    __syncthreads();
    if (tid == 0) {
        int r = 0;
        #pragma unroll
        for (int i = 0; i < 16; i++) { int c = wsum[i]; woff[i] = r; r += c; }
    }
    __syncthreads();
    int run = woff[w] + (v - s);
    for (int i = lo; i < hi; i++) {
        base[i] = run; cursor[i] = run;
        run += cnt[i];
    }
    __syncthreads();   // base[] globally written by this block
    if (tid < 8) {
        int blo_i = min(tid * bsz, N);
        int bhi_i = min((tid + 1) * bsz, N);
        int blo = (blo_i >= N) ? E : base[blo_i];
        int bhi = (bhi_i >= N) ? E : base[bhi_i];
        binfo[8 + tid] = blo;
        binfo[tid]     = bhi - blo;
    }
}

__global__ void scatter2_kernel(const int* __restrict__ edst, int E,
                                int* __restrict__ cursor, int* __restrict__ perm)
{
    for (int e = blockIdx.x * blockDim.x + threadIdx.x; e < E;
         e += gridDim.x * blockDim.x) {
        int p = atomicAdd(&cursor[edst[e]], 1);
        perm[p] = e;
    }
}

// ---------------------------------------------------------------------------
// Edge kernel (R18, unchanged): K=64 macro-steps, 2x16KB LDS slots, 2-set
// register prefetch, per-thread meta, fp16 emb tables, fast silu,
// single-pass fp32-M epilogue with run-length atomics.
// ---------------------------------------------------------------------------
__global__ void __launch_bounds__(256, 3)
edge_mfma(const _Float16* __restrict__ h16,
          const int* __restrict__ perm, const int* __restrict__ binfo,
          const int* __restrict__ esrc, const int* __restrict__ edst,
          const int* __restrict__ erel, const int* __restrict__ ncol,
          const int* __restrict__ nrole,
          const float* __restrict__ rel_emb, const float* __restrict__ role_emb,
          const float* __restrict__ col_emb,
          const _Float16* __restrict__ wef,   // [14][4096] fragment-order
          const float* __restrict__ eb1, const float* __restrict__ eb2,
          float* __restrict__ agg)
{
    __shared__ __align__(16) unsigned char uR[50176];
    __shared__ int sDst[64];
    __shared__ __align__(16) _Float16 sRelE[128];
    __shared__ __align__(16) _Float16 sRoleE[48];
    __shared__ __align__(16) _Float16 sColE[24];

    _Float16* sB = (_Float16*)uR;               // 2 x 8192 halfs
    _Float16* sY = (_Float16*)(uR + 32768);     // [64][136]
    float*    M  = (float*)uR;                  // [64][132]

    const int tid  = threadIdx.x;
    const int lane = tid & 63;
    const int wv   = tid >> 6;
    const int lm   = lane & 15;
    const int lh   = lane >> 4;

    if (tid < 128) sRelE[tid] = (_Float16)rel_emb[tid];
    if (tid < 48)  sRoleE[tid] = (_Float16)role_emb[tid];
    if (tid < 24)  sColE[tid] = (_Float16)col_emb[tid];

    const int bucket = blockIdx.x;
    const int bcount = binfo[bucket];
    const int bbase  = binfo[8 + bucket];

    const int r0 = wv * 16 + lm;
    const _Float16* wp = wef + tid * 16;

    float bias1[8], bias2[8];
    #pragma unroll
    for (int f = 0; f < 8; f++) { bias1[f] = eb1[f * 16 + lm]; bias2[f] = eb2[f * 16 + lm]; }

    for (int t = blockIdx.y; t * 64 < bcount; t += gridDim.y)
    {
        lgkm_barrier();

        const int idx   = t * 64 + r0;
        const int valid = idx < bcount;
        const int e     = perm[bbase + (valid ? idx : 0)];
        const int mSrc  = esrc[e];
        const int d     = edst[e];
        const int mRel  = erel[e];
        const int mRS = nrole[mSrc], mRD = nrole[d];
        const int mCS = ncol[mSrc],  mCD = ncol[d];
        const int mDst = valid ? d : -1;
        if (lh == 0) sDst[r0] = mDst;

        half8 a[8];
        {
            const int adst = mDst < 0 ? mSrc : mDst;
            const _Float16* sp = &h16[(size_t)mSrc * H + lh * 8];
            const _Float16* dp = &h16[(size_t)adst * H + lh * 8];
            #pragma unroll
            for (int q = 0; q < 4; q++) a[q]     = *(const half8*)(sp + q * 32);
            #pragma unroll
            for (int q = 0; q < 4; q++) a[4 + q] = *(const half8*)(dp + q * 32);
        }

        half8 e8, e9;
        {
            const _Float16* pe8 = (lh == 0) ? &sRelE[mRel * 16]
                                : (lh == 1) ? &sRelE[mRel * 16 + 8]
                                : (lh == 2) ? &sRoleE[mRS * 8]
                                            : &sRoleE[mRD * 8];
            e8 = *(const half8*)pe8;
            if (lh < 2) {
                const _Float16* pe9 = (lh == 0) ? &sColE[mCS * 8] : &sColE[mCD * 8];
                e9 = *(const half8*)pe9;
            } else {
                #pragma unroll
                for (int j = 0; j < 8; j++) e9[j] = (_Float16)0.0f;
            }
        }

        half8 pf[2][4];
        {
            half8 x0 = *(const half8*)(wp);
            half8 x1 = *(const half8*)(wp + 8);
            half8 x2 = *(const half8*)(wp + 4096);
            half8 x3 = *(const half8*)(wp + 4096 + 8);
            _Float16* w = &sB[tid * 16];
            *(half8*)(w)            = x0;
            *(half8*)(w + 8)        = x1;
            *(half8*)(w + 4096)     = x2;
            *(half8*)(w + 4096 + 8) = x3;
            pf[1][0] = *(const half8*)(wp + 2 * 4096);
            pf[1][1] = *(const half8*)(wp + 2 * 4096 + 8);
            pf[1][2] = *(const half8*)(wp + 3 * 4096);
            pf[1][3] = *(const half8*)(wp + 3 * 4096 + 8);
        }

        floatx4 acc[8];
        #pragma unroll
        for (int f = 0; f < 8; f++) acc[f] = (floatx4){0.f, 0.f, 0.f, 0.f};

        lgkm_barrier();

        #pragma unroll
        for (int s = 0; s < 5; s++) {
            if (s + 2 <= 6) {
                const _Float16* bp = wp + (size_t)(2 * (s + 2)) * 4096;
                pf[s & 1][0] = *(const half8*)(bp);
                pf[s & 1][1] = *(const half8*)(bp + 8);
                pf[s & 1][2] = *(const half8*)(bp + 4096);
                pf[s & 1][3] = *(const half8*)(bp + 4096 + 8);
            }
            #pragma unroll
            for (int hh = 0; hh < 2; hh++) {
                half8 af = (s < 4) ? a[2 * s + hh] : (hh == 0 ? e8 : e9);
                #pragma unroll
                for (int f = 0; f < 8; f++) {
                    half8 bf = *(const half8*)&sB[(s & 1) * 8192 + hh * 4096 + (f * 64 + lane) * 8];
                    acc[f] = __builtin_amdgcn_mfma_f32_16x16x32_f16(af, bf, acc[f], 0, 0, 0);
                }
            }
            {
                _Float16* w = &sB[((s + 1) & 1) * 8192 + tid * 16];
                *(half8*)(w)            = pf[(s + 1) & 1][0];
                *(half8*)(w + 8)        = pf[(s + 1) & 1][1];
                *(half8*)(w + 4096)     = pf[(s + 1) & 1][2];
                *(half8*)(w + 4096 + 8) = pf[(s + 1) & 1][3];
            }
            if (s < 4) lgkm_barrier();
        }

        #pragma unroll
        for (int f = 0; f < 8; f++) {
            const int col = f * 16 + lm;
            #pragma unroll
            for (int v = 0; v < 4; v++) {
                const int row = wv * 16 + lh * 4 + v;
                sY[row * 136 + col] = (_Float16)silu_f(acc[f][v] + bias1[f]);
            }
        }
        lgkm_barrier();

        floatx4 acc2[8];
        #pragma unroll
        for (int f = 0; f < 8; f++) acc2[f] = (floatx4){0.f, 0.f, 0.f, 0.f};

        #pragma unroll
        for (int hh = 0; hh < 2; hh++) {
            half8 af = *(const half8*)&sY[r0 * 136 + hh * 32 + lh * 8];
            #pragma unroll
            for (int f = 0; f < 8; f++) {
                half8 bf = *(const half8*)&sB[8192 + hh * 4096 + (f * 64 + lane) * 8];
                acc2[f] = __builtin_amdgcn_mfma_f32_16x16x32_f16(af, bf, acc2[f], 0, 0, 0);
            }
        }
        {
            _Float16* w = &sB[tid * 16];
            *(half8*)(w)            = pf[0][0];
            *(half8*)(w + 8)        = pf[0][1];
            *(half8*)(w + 4096)     = pf[0][2];
            *(half8*)(w + 4096 + 8) = pf[0][3];
        }
        lgkm_barrier();

        #pragma unroll
        for (int hh = 0; hh < 2; hh++) {
            half8 af = *(const half8*)&sY[r0 * 136 + 64 + hh * 32 + lh * 8];
            #pragma unroll
            for (int f = 0; f < 8; f++) {
                half8 bf = *(const half8*)&sB[hh * 4096 + (f * 64 + lane) * 8];
                acc2[f] = __builtin_amdgcn_mfma_f32_16x16x32_f16(af, bf, acc2[f], 0, 0, 0);
            }
        }
        lgkm_barrier();

        #pragma unroll
        for (int f = 0; f < 8; f++) {
            const int col = f * 16 + lm;
            #pragma unroll
            for (int v = 0; v < 4; v++) {
                const int row = wv * 16 + lh * 4 + v;
                M[row * 132 + col] = silu_f(acc2[f][v] + bias2[f]);
            }
        }
        lgkm_barrier();
        {
            const int c  = tid & 127;
            const int g  = tid >> 7;
            const int rb = g * 32;
            float m[32]; int dd[32];
            #pragma unroll
            for (int i = 0; i < 32; i++) {
                m[i]  = M[(rb + i) * 132 + c];
                dd[i] = sDst[rb + i];
            }
            float acz = 0.0f; int cur = -1;
            #pragma unroll
            for (int i = 0; i < 32; i++) {
                if (dd[i] != cur) {
                    if (cur >= 0) unsafeAtomicAdd(&agg[cur * H + c], acz);
                    acz = 0.0f; cur = dd[i];
                }
                if (dd[i] >= 0) acz += m[i];
            }
            if (cur >= 0) unsafeAtomicAdd(&agg[cur * H + c], acz);
        }
    }
}

// ---------------------------------------------------------------------------
// Node kernel, fast path (R18, unchanged).
// ---------------------------------------------------------------------------
__global__ void __launch_bounds__(256, 4)
node_fast(const _Float16* __restrict__ h16, const float* __restrict__ agg,
          const float* __restrict__ h,
          const int* __restrict__ ncol, const int* __restrict__ nrole,
          const float* __restrict__ role_emb, const float* __restrict__ col_emb,
          const _Float16* __restrict__ nwf,   // [13][4096]
          const float* __restrict__ nb1, const float* __restrict__ nb2,
          const float* __restrict__ ln_g, const float* __restrict__ ln_b,
          float* __restrict__ out, int N)
{
    __shared__ __align__(16) _Float16 sB[2 * 4096];
    __shared__ __align__(16) _Float16 sY[64 * 136];
    __shared__ int sRole[64], sCol[64];
    __shared__ __align__(16) _Float16 sRoleE[48];
    __shared__ __align__(16) _Float16 sColE[24];

    const int tid  = threadIdx.x;
    const int lane = tid & 63;
    const int wv   = tid >> 6;
    const int lm   = lane & 15;
    const int lh   = lane >> 4;
    const int n0   = blockIdx.x * 64;
    const int r0   = wv * 16 + lm;
    const _Float16* wp = nwf + tid * 16;

    if (tid < 48) sRoleE[tid] = (_Float16)role_emb[tid];
    if (tid < 24) sColE[tid] = (_Float16)col_emb[tid];
    if (tid < 64) {
        int n = n0 + tid; if (n >= N) n = N - 1;
        sRole[tid] = nrole[n];
        sCol[tid]  = ncol[n];
    }

    half8 a[8];
    {
        int n = n0 + r0; if (n >= N) n = N - 1;
        const _Float16* hp = h16 + (size_t)n * H + lh * 8;
        #pragma unroll
        for (int s = 0; s < 4; s++) a[s] = *(const half8*)(hp + s * 32);
        const float* ap = agg + (size_t)n * H + lh * 8;
        #pragma unroll
        for (int s = 0; s < 4; s++) {
            float4 x = *(const float4*)(ap + s * 32);
            float4 y = *(const float4*)(ap + s * 32 + 4);
            a[4 + s] = cvt8(x, y);
        }
    }

    half8 pfa[3], pfb[3];
    {
        half8 s0a = *(const half8*)(wp);
        half8 s0b = *(const half8*)(wp + 8);
        *(half8*)&sB[tid * 16]     = s0a;
        *(half8*)&sB[tid * 16 + 8] = s0b;
        pfa[1] = *(const half8*)(wp + 1 * 4096);
        pfb[1] = *(const half8*)(wp + 1 * 4096 + 8);
        pfa[2] = *(const half8*)(wp + 2 * 4096);
        pfb[2] = *(const half8*)(wp + 2 * 4096 + 8);
    }

    floatx4 acc[8];
    #pragma unroll
    for (int f = 0; f < 8; f++) acc[f] = (floatx4){0.f, 0.f, 0.f, 0.f};

    lgkm_barrier();

    #pragma unroll
    for (int s = 0; s < 9; s++) {
        if (s + 3 <= 12) {
            pfa[s % 3] = *(const half8*)(wp + (s + 3) * 4096);
            pfb[s % 3] = *(const half8*)(wp + (s + 3) * 4096 + 8);
        }
        half8 af;
        if (s < 8) {
            af = a[s];
        } else {
            if (lh < 2) {
                const _Float16* p = (lh == 0) ? &sRoleE[sRole[r0] * 8] : &sColE[sCol[r0] * 8];
                af = *(const half8*)p;
            } else {
                #pragma unroll
                for (int j = 0; j < 8; j++) af[j] = (_Float16)0.0f;
            }
        }
        #pragma unroll
        for (int f = 0; f < 8; f++) {
            half8 bf = *(const half8*)&sB[(s & 1) * 4096 + (f * 64 + lane) * 8];
            acc[f] = __builtin_amdgcn_mfma_f32_16x16x32_f16(af, bf, acc[f], 0, 0, 0);
        }
        {
            _Float16* wdst = &sB[((s + 1) & 1) * 4096 + tid * 16];
            *(half8*)(wdst)     = pfa[(s + 1) % 3];
            *(half8*)(wdst + 8) = pfb[(s + 1) % 3];
        }
        lgkm_barrier();
    }

    #pragma unroll
    for (int f = 0; f < 8; f++) {
        const int col = f * 16 + lm;
        const float b1 = nb1[col];
        #pragma unroll
        for (int v = 0; v < 4; v++) {
            const int row = wv * 16 + lh * 4 + v;
            sY[row * 136 + col] = (_Float16)silu_f(acc[f][v] + b1);
        }
    }
    asm volatile("s_waitcnt lgkmcnt(0)" ::: "memory");
    __builtin_amdgcn_sched_barrier(0);

    floatx4 acc2[8];
    #pragma unroll
    for (int f = 0; f < 8; f++) acc2[f] = (floatx4){0.f, 0.f, 0.f, 0.f};

    #pragma unroll
    for (int s2 = 0; s2 < 4; s2++) {
        const int s = 9 + s2;
        if (s + 3 <= 12) {
            pfa[s % 3] = *(const half8*)(wp + (s + 3) * 4096);
            pfb[s % 3] = *(const half8*)(wp + (s + 3) * 4096 + 8);
        }
        half8 af = *(const half8*)&sY[r0 * 136 + s2 * 32 + lh * 8];
        #pragma unroll
        for (int f = 0; f < 8; f++) {
            half8 bf = *(const half8*)&sB[(s & 1) * 4096 + (f * 64 + lane) * 8];
            acc2[f] = __builtin_amdgcn_mfma_f32_16x16x32_f16(af, bf, acc2[f], 0, 0, 0);
        }
        if (s <= 11) {
            _Float16* wdst = &sB[((s + 1) & 1) * 4096 + tid * 16];
            *(half8*)(wdst)     = pfa[(s + 1) % 3];
            *(half8*)(wdst + 8) = pfb[(s + 1) % 3];
        }
        if (s2 < 3) lgkm_barrier();
    }

    float g[8], bb[8], b2[8];
    #pragma unroll
    for (int f = 0; f < 8; f++) {
        const int col = f * 16 + lm;
        g[f]  = ln_g[col];
        bb[f] = ln_b[col];
        b2[f] = nb2[col];
    }
    #pragma unroll
    for (int v = 0; v < 4; v++) {
        const int row = n0 + wv * 16 + lh * 4 + v;
        const int rc  = row < N ? row : N - 1;
        float x[8];
        float sum = 0.0f;
        #pragma unroll
        for (int f = 0; f < 8; f++) {
            const int col = f * 16 + lm;
            x[f] = h[(size_t)rc * H + col] + acc2[f][v] + b2[f];
            sum += x[f];
        }
        sum += __shfl_xor(sum, 1);
        sum += __shfl_xor(sum, 2);
        sum += __shfl_xor(sum, 4);
        sum += __shfl_xor(sum, 8);
        const float mu = sum * (1.0f / 128.0f);
        float vs = 0.0f;
        #pragma unroll
        for (int f = 0; f < 8; f++) { float dx = x[f] - mu; vs += dx * dx; }
        vs += __shfl_xor(vs, 1);
        vs += __shfl_xor(vs, 2);
        vs += __shfl_xor(vs, 4);
        vs += __shfl_xor(vs, 8);
        const float rstd = rsqrtf(vs * (1.0f / 128.0f) + LN_EPS);
        if (row < N) {
            #pragma unroll
            for (int f = 0; f < 8; f++) {
                const int col = f * 16 + lm;
                out[(size_t)row * H + col] = (x[f] - mu) * rstd * g[f] + bb[f];
            }
        }
    }
}

// ---------------------------------------------------------------------------
// Node kernel fallback (reads only d_in / d_ws).
// ---------------------------------------------------------------------------
__global__ void __launch_bounds__(256)
node_mfma(const float* __restrict__ h, const float* __restrict__ agg,
          const int* __restrict__ ncol, const int* __restrict__ nrole,
          const float* __restrict__ role_emb, const float* __restrict__ col_emb,
          const float* __restrict__ nW1, const float* __restrict__ nb1,
          const float* __restrict__ nW2, const float* __restrict__ nb2,
          const float* __restrict__ ln_g, const float* __restrict__ ln_b,
          float* __restrict__ out, int N)
{
    __shared__ _Float16 sA[64 * 40];
    __shared__ _Float16 sB[128 * 40];
    __shared__ _Float16 sY[64 * 136];
    __shared__ int sRole[64], sCol[64];
    __shared__ float sRoleE[48], sColE[24];

    const int tid  = threadIdx.x;
    const int lane = tid & 63;
    const int wv   = tid >> 6;
    const int lm   = lane & 15;
    const int lh   = lane >> 4;
    const int n0   = blockIdx.x * 64;

    if (tid < 48) sRoleE[tid] = role_emb[tid];
    if (tid < 24) sColE[tid] = col_emb[tid];
    if (tid < 64) {
        int n = n0 + tid; if (n >= N) n = N - 1;
        sRole[tid] = nrole[n];
        sCol[tid]  = ncol[n];
    }

    floatx4 acc[8];
    #pragma unroll
    for (int f = 0; f < 8; f++) acc[f] = (floatx4){0.f, 0.f, 0.f, 0.f};

    __syncthreads();

    for (int s = 0; s < 9; s++) {
        const int k0 = s * 32;
        {
            const int r  = tid >> 2;
            const int kq = (tid & 3) * 8;
            const int k  = k0 + kq;
            int n = n0 + r; if (n >= N) n = N - 1;
            float v[8];
            if (k < 128) {
                const float4* p = (const float4*)&h[n * H + k];
                float4 a = p[0], b = p[1];
                v[0]=a.x; v[1]=a.y; v[2]=a.z; v[3]=a.w;
                v[4]=b.x; v[5]=b.y; v[6]=b.z; v[7]=b.w;
            } else if (k < 256) {
                const float4* p = (const float4*)&agg[n * H + (k - 128)];
                float4 a = p[0], b = p[1];
                v[0]=a.x; v[1]=a.y; v[2]=a.z; v[3]=a.w;
                v[4]=b.x; v[5]=b.y; v[6]=b.z; v[7]=b.w;
            } else if (k < 264) {
                const float* p = &sRoleE[sRole[r] * 8 + (k - 256)];
                #pragma unroll
                for (int j = 0; j < 8; j++) v[j] = p[j];
            } else if (k < 272) {
                const float* p = &sColE[sCol[r] * 8 + (k - 264)];
                #pragma unroll
                for (int j = 0; j < 8; j++) v[j] = p[j];
            } else {
                #pragma unroll
                for (int j = 0; j < 8; j++) v[j] = 0.0f;
            }
            half8 o;
            #pragma unroll
            for (int j = 0; j < 8; j++) o[j] = (_Float16)v[j];
            *(half8*)&sA[r * 40 + kq] = o;
        }
        {
            const int n  = tid & 127;
            const int kh = (tid >> 7) * 16;
            #pragma unroll
            for (int i = 0; i < 16; i += 2) {
                const int ka = k0 + kh + i;
                const int kb = ka + 1;
                float wa = (ka < 272) ? nW1[ka * H + n] : 0.0f;
                float wb = (kb < 272) ? nW1[kb * H + n] : 0.0f;
                union { _Float16 f[2]; unsigned u; } pk;
                pk.f[0] = (_Float16)wa; pk.f[1] = (_Float16)wb;
                *(unsigned*)&sB[n * 40 + kh + i] = pk.u;
            }
        }
        __syncthreads();
        half8 af = *(const half8*)&sA[(wv * 16 + lm) * 40 + lh * 8];
        #pragma unroll
        for (int f = 0; f < 8; f++) {
            half8 bf = *(const half8*)&sB[(f * 16 + lm) * 40 + lh * 8];
            acc[f] = __builtin_amdgcn_mfma_f32_16x16x32_f16(af, bf, acc[f], 0, 0, 0);
        }
        __syncthreads();
    }

    #pragma unroll
    for (int f = 0; f < 8; f++) {
        const int col = f * 16 + lm;
        const float b1 = nb1[col];
        #pragma unroll
        for (int v = 0; v < 4; v++) {
            const int row = wv * 16 + lh * 4 + v;
            sY[row * 136 + col] = (_Float16)silu_f(acc[f][v] + b1);
        }
    }

    floatx4 acc2[8];
    #pragma unroll
    for (int f = 0; f < 8; f++) acc2[f] = (floatx4){0.f, 0.f, 0.f, 0.f};

    __syncthreads();

    for (int s2 = 0; s2 < 4; s2++) {
        {
            const int n  = tid & 127;
            const int kh = (tid >> 7) * 16;
            #pragma unroll
            for (int i = 0; i < 16; i += 2) {
                const int ka = s2 * 32 + kh + i;
                float wa = nW2[ka * H + n];
                float wb = nW2[(ka + 1) * H + n];
                union { _Float16 f[2]; unsigned u; } pk;
                pk.f[0] = (_Float16)wa; pk.f[1] = (_Float16)wb;
                *(unsigned*)&sB[n * 40 + kh + i] = pk.u;
            }
        }
        __syncthreads();
        half8 af = *(const half8*)&sY[(wv * 16 + lm) * 136 + s2 * 32 + lh * 8];
        #pragma unroll
        for (int f = 0; f < 8; f++) {
            half8 bf = *(const half8*)&sB[(f * 16 + lm) * 40 + lh * 8];
            acc2[f] = __builtin_amdgcn_mfma_f32_16x16x32_f16(af, bf, acc2[f], 0, 0, 0);
        }
        __syncthreads();
    }

    float g[8], bb[8], b2[8];
    #pragma unroll
    for (int f = 0; f < 8; f++) {
        const int col = f * 16 + lm;
        g[f]  = ln_g[col];
        bb[f] = ln_b[col];
        b2[f] = nb2[col];
    }
    #pragma unroll
    for (int v = 0; v < 4; v++) {
        const int row = n0 + wv * 16 + lh * 4 + v;
        const int rc  = row < N ? row : N - 1;
        float x[8];
        float sum = 0.0f;
        #pragma unroll
        for (int f = 0; f < 8; f++) {
            const int col = f * 16 + lm;
            x[f] = h[rc * H + col] + acc2[f][v] + b2[f];
            sum += x[f];
        }
        sum += __shfl_xor(sum, 1);
        sum += __shfl_xor(sum, 2);
        sum += __shfl_xor(sum, 4);
        sum += __shfl_xor(sum, 8);
        const float mu = sum * (1.0f / 128.0f);
        float vs = 0.0f;
        #pragma unroll
        for (int f = 0; f < 8; f++) { float dx = x[f] - mu; vs += dx * dx; }
        vs += __shfl_xor(vs, 1);
        vs += __shfl_xor(vs, 2);
        vs += __shfl_xor(vs, 4);
        vs += __shfl_xor(vs, 8);
        const float rstd = rsqrtf(vs * (1.0f / 128.0f) + LN_EPS);
        if (row < N) {
            #pragma unroll
            for (int f = 0; f < 8; f++) {
                const int col = f * 16 + lm;
                out[row * H + col] = (x[f] - mu) * rstd * g[f] + bb[f];
            }
        }
    }
}

extern "C" void kernel_launch(void* const* d_in, const int* in_sizes, int n_in,
                              void* d_out, int out_size, void* d_ws, size_t ws_size,
                              hipStream_t stream)
{
    const float* h        = (const float*)d_in[0];
    const int*   eidx     = (const int*)d_in[1];
    const int*   erel     = (const int*)d_in[2];
    const int*   ncol     = (const int*)d_in[3];
    const int*   nrole    = (const int*)d_in[4];
    const float* rel_emb  = (const float*)d_in[5];
    const float* role_emb = (const float*)d_in[6];
    const float* col_emb  = (const float*)d_in[7];
    const float* eW1      = (const float*)d_in[8];
    const float* eb1      = (const float*)d_in[9];
    const float* eW2      = (const float*)d_in[10];
    const float* eb2      = (const float*)d_in[11];
    const float* nW1      = (const float*)d_in[12];
    const float* nb1      = (const float*)d_in[13];
    const float* nW2      = (const float*)d_in[14];
    const float* nb2      = (const float*)d_in[15];
    const float* ln_g     = (const float*)d_in[16];
    const float* ln_b     = (const float*)d_in[17];

    const int N = in_sizes[0] / H;
    const int E = in_sizes[2];
    const int* esrc = eidx;
    const int* edst = eidx + E;
    const int bsz = (N + 7) / 8;

    float* agg = (float*)d_ws;

    // Sort scratch in d_out (dead before the node kernel writes out).
    int* perm   = (int*)d_out;
    int* cnt    = perm + E;
    int* base   = cnt + N;
    int* cursor = base + N;
    int* binfo  = cursor + N;

    size_t aggB   = (size_t)N * H * sizeof(float);
    size_t needWs = aggB + (size_t)N * H * 2 + (14 + 13) * 4096 * 2;
    const bool fast = (ws_size >= needWs);

    _Float16 *h16, *wef, *nwf;
    if (fast) {
        h16 = (_Float16*)((char*)d_ws + aggB);
        wef = h16 + (size_t)N * H;
        nwf = wef + 14 * 4096;
    } else {
        size_t io = (size_t)(E + 3 * N + 16);
        io = (io + 7) & ~(size_t)7;
        h16 = (_Float16*)(perm + io);
        wef = h16 + (size_t)N * H;
        nwf = wef + 14 * 4096;
    }

    // Fused prep: zero agg + cnt, cvt h16, cvt weights (one dispatch).
    const int nagg4 = N * H / 4;
    const int nh8   = N * H / 8;
    const int total = nagg4 + nh8 + 27 * 4096 + N;
    prep_kernel<<<(total + 255) / 256, 256, 0, stream>>>(
        h, h16, nh8, eW1, eW2, nW1, nW2, wef, nwf, agg, nagg4, cnt, N);

    hist2_kernel<<<512, 256, 0, stream>>>(edst, E, cnt);
    scan2_kernel<<<1, 1024, 0, stream>>>(cnt, base, cursor, N, bsz, E, binfo);
    scatter2_kernel<<<512, 256, 0, stream>>>(edst, E, cursor, perm);

    dim3 egrid(8, 96);
    edge_mfma<<<egrid, 256, 0, stream>>>(
        h16, perm, binfo, esrc, edst, erel, ncol, nrole,
        rel_emb, role_emb, col_emb, wef, eb1, eb2, agg);

    if (fast) {
        node_fast<<<(N + 63) / 64, 256, 0, stream>>>(
            h16, agg, h, ncol, nrole, role_emb, col_emb,
            nwf, nb1, nb2, ln_g, ln_b, (float*)d_out, N);
    } else {
        node_mfma<<<(N + 63) / 64, 256, 0, stream>>>(
            h, agg, ncol, nrole, role_emb, col_emb,
            nW1, nb1, nW2, nb2, ln_g, ln_b, (float*)d_out, N);
    }
}